// Round 7
// baseline (567.851 us; speedup 1.0000x reference)
//
#include <hip/hip_runtime.h>
#include <hip/hip_bf16.h>

#define NT 4096          // B*T tokens
#define HD 2048          // hidden
#define NE 8             // experts
#define TOPK 2
#define ID 1408          // intermediate
#define NG 9             // 8 experts + shared
#define BM 128
#define BN 128
#define BK 32
#define MT_MAX 104       // max sum of ceil(cnt/128) over groups (<=72) + 32 shared

typedef unsigned short u16;
typedef unsigned int u32;
typedef unsigned long long u64;
typedef __attribute__((ext_vector_type(8))) short bf16x8;
typedef __attribute__((ext_vector_type(4))) float f32x4;

__device__ __forceinline__ u16 f2bf(float f) {
    u32 u = __builtin_bit_cast(u32, f);
    u += 0x7FFFu + ((u >> 16) & 1u);   // round-to-nearest-even
    return (u16)(u >> 16);
}
__device__ __forceinline__ float bflo(u32 v) { return __builtin_bit_cast(float, v << 16); }
__device__ __forceinline__ float bfhi(u32 v) { return __builtin_bit_cast(float, v & 0xffff0000u); }

// async global->LDS, 16B per lane; lds base must be wave-uniform
typedef __attribute__((address_space(1))) const void gas_void;
typedef __attribute__((address_space(3))) void las_void;
__device__ __forceinline__ void gl_lds16(const void* g, void* l) {
    __builtin_amdgcn_global_load_lds((gas_void*)(u64)g, (las_void*)(u32)(u64)l, 16, 0, 0);
}

// decode staging slot s -> (tile row, 16B quad) for the 2-row-packed XOR layout:
// LDS line L (128B) holds tile rows {2L,2L+1}; chunk c stored at c ^ (L&7).
__device__ __forceinline__ void decode_slot(int s, int& r, int& q) {
    int L = s >> 3;
    int c = (s & 7) ^ (L & 7);
    r = 2 * L + (c >> 2);
    q = c & 3;
}

// ---------------- router + x->bf16 perm convert (fused) ---------------------
__global__ void router_kernel(const float* __restrict__ x, const float* __restrict__ gw,
                              int* __restrict__ counts, float* __restrict__ imp,
                              int* __restrict__ tki, float* __restrict__ tkv,
                              u16* __restrict__ xb) {
    __shared__ float s_imp[NE];
    __shared__ int s_cnt[NE];
    if (threadIdx.x < NE) { s_imp[threadIdx.x] = 0.f; s_cnt[threadIdx.x] = 0; }
    int w = threadIdx.x >> 6, lane = threadIdx.x & 63;
    int t = blockIdx.x * 4 + w;
    float acc[NE];
#pragma unroll
    for (int e = 0; e < NE; e++) acc[e] = 0.f;
    const float* xr = x + (size_t)t * HD;
    u16* xw = xb + (size_t)t * HD;
#pragma unroll
    for (int i = 0; i < 4; i++) {
        int cc = i * 64 + lane;
        int b64 = cc >> 3, j = cc & 7, h = j >> 2, q = j & 3;
        int k0 = b64 * 64 + h * 32 + q * 4;
        float4 v0 = *(const float4*)(xr + k0);
        float4 v1 = *(const float4*)(xr + k0 + 16);
#pragma unroll
        for (int e = 0; e < NE; e++) {
            const float* gp = gw + e * HD + k0;
            float4 g0 = *(const float4*)(gp);
            float4 g1 = *(const float4*)(gp + 16);
            acc[e] += v0.x * g0.x + v0.y * g0.y + v0.z * g0.z + v0.w * g0.w
                    + v1.x * g1.x + v1.y * g1.y + v1.z * g1.z + v1.w * g1.w;
        }
        ushort4 o0, o1;
        o0.x = f2bf(v0.x); o0.y = f2bf(v0.y); o0.z = f2bf(v0.z); o0.w = f2bf(v0.w);
        o1.x = f2bf(v1.x); o1.y = f2bf(v1.y); o1.z = f2bf(v1.z); o1.w = f2bf(v1.w);
        uint4 o;
        o.x = (u32)o0.x | ((u32)o0.y << 16); o.y = (u32)o0.z | ((u32)o0.w << 16);
        o.z = (u32)o1.x | ((u32)o1.y << 16); o.w = (u32)o1.z | ((u32)o1.w << 16);
        *(uint4*)(xw + b64 * 64 + j * 8) = o;
    }
#pragma unroll
    for (int e = 0; e < NE; e++) {
#pragma unroll
        for (int o = 32; o >= 1; o >>= 1) acc[e] += __shfl_xor(acc[e], o, 64);
    }
    __syncthreads();
    if (lane == 0) {
        float mx = acc[0];
        for (int e = 1; e < NE; e++) mx = fmaxf(mx, acc[e]);
        float p[NE], sum = 0.f;
        for (int e = 0; e < NE; e++) { p[e] = expf(acc[e] - mx); sum += p[e]; }
        float inv = 1.f / sum;
        for (int e = 0; e < NE; e++) p[e] *= inv;
        int i1 = 0;
        for (int e = 1; e < NE; e++) if (p[e] > p[i1]) i1 = e;
        int i2 = (i1 == 0) ? 1 : 0;
        for (int e = 0; e < NE; e++) if (e != i1 && p[e] > p[i2]) i2 = e;
        tki[t * 2 + 0] = i1; tkv[t * 2 + 0] = p[i1];
        tki[t * 2 + 1] = i2; tkv[t * 2 + 1] = p[i2];
        for (int e = 0; e < NE; e++) atomicAdd(&s_imp[e], p[e]);
        atomicAdd(&s_cnt[i1], 1); atomicAdd(&s_cnt[i2], 1);
    }
    __syncthreads();
    if (threadIdx.x < NE) {
        atomicAdd(&imp[threadIdx.x], s_imp[threadIdx.x]);
        atomicAdd(&counts[threadIdx.x], s_cnt[threadIdx.x]);
    }
}

// ---------------- prep -------------------------------------------------------
__global__ void prep_kernel(const int* __restrict__ counts, const float* __restrict__ imp,
                            int* __restrict__ off, int* __restrict__ tileoff,
                            float* __restrict__ out_aux) {
    if (threadIdx.x == 0 && blockIdx.x == 0) {
        int o = 0, to = 0;
        for (int g = 0; g < NG; g++) {
            int c = (g < NE) ? counts[g] : NT;
            off[g] = o; tileoff[g] = to;
            o += c; to += (c + BM - 1) / BM;
        }
        off[NG] = o; tileoff[NG] = to;
        float aux = 0.f;
        for (int e = 0; e < NE; e++)
            aux += (imp[e] / (float)NT) * ((float)counts[e] / (float)(NT * TOPK));
        *out_aux = aux * (float)NE;
    }
}

// ---------------- scatter: token lists + slot map (overwrites tki) ----------
__global__ void scatter_kernel(int* __restrict__ tki, const float* __restrict__ tkv,
                               const int* __restrict__ off, int* __restrict__ cursor,
                               int* __restrict__ list, float* __restrict__ wgt) {
    int t = blockIdx.x * blockDim.x + threadIdx.x;
    if (t >= NT) return;
#pragma unroll
    for (int k = 0; k < TOPK; k++) {
        int e = tki[t * 2 + k];
        int pos = atomicAdd(&cursor[e], 1);
        int s = off[e] + pos;
        list[s] = t;
        wgt[s] = tkv[t * 2 + k];
        tki[t * 2 + k] = s;
    }
    list[off[NE] + t] = t;
    wgt[off[NE] + t] = 1.0f;
}

// ---------------- transpose+convert weights (experts + shared in one grid) --
__global__ void transw_kernel(const float* __restrict__ W, const float* __restrict__ Wsh,
                              u16* __restrict__ dst, int K, int N) {
    int e = blockIdx.z;
    const float* src = (e < NE) ? (W + (size_t)e * K * N) : Wsh;
    dst += (size_t)e * N * K;
    int k0 = blockIdx.y * 64, n0 = blockIdx.x * 64;
    __shared__ u16 Lt[64][68];
    int tid = threadIdx.x;
#pragma unroll
    for (int i = 0; i < 4; i++) {
        int idx = i * 256 + tid;
        int kl = idx >> 4, nq = (idx & 15) * 4;
        float4 v = *(const float4*)(src + (size_t)(k0 + kl) * N + n0 + nq);
        Lt[nq + 0][kl] = f2bf(v.x); Lt[nq + 1][kl] = f2bf(v.y);
        Lt[nq + 2][kl] = f2bf(v.z); Lt[nq + 3][kl] = f2bf(v.w);
    }
    __syncthreads();
#pragma unroll
    for (int c2 = 0; c2 < 2; c2++) {
        int cid = tid * 2 + c2;
        int nr = cid >> 3, j = cid & 7;
        int h = j >> 2, q = j & 3;
        int kb = h * 32 + q * 4;
        uint2 lo = *(const uint2*)&Lt[nr][kb];
        uint2 hi = *(const uint2*)&Lt[nr][kb + 16];
        uint4 o; o.x = lo.x; o.y = lo.y; o.z = hi.x; o.w = hi.y;
        *(uint4*)(dst + (size_t)(n0 + nr) * K + k0 + j * 8) = o;
    }
}

// ---------------- fc1: h1 = SiLU(xb_gathered @ Wt1_g^T), perm'd bf16 out ----
// 128x128 tile, BK=32, 32KB LDS dbuf (5 blocks/CU), counted vmcnt(4),
// 2-row-packed XOR-swizzled LDS (conflict-free 2-way).
__global__ __launch_bounds__(256, 5) void fc1_kernel(
    const u16* __restrict__ xb, const u16* __restrict__ Wt1,
    const int* __restrict__ off, const int* __restrict__ tileoff,
    const int* __restrict__ list, u16* __restrict__ h1) {
    __shared__ u16 S[16384];   // 2 bufs x (A 8KB + B 8KB)
    int nwg = gridDim.x * gridDim.y;           // 11*104 = 1144, %8==0
    int orig = blockIdx.y * gridDim.x + blockIdx.x;
    int wg = (orig & 7) * (nwg >> 3) + (orig >> 3);
    int bx = wg % gridDim.x, mt = wg / gridDim.x;

    int g = -1, gto = 0;
#pragma unroll
    for (int gg = 0; gg < NG; gg++)
        if (mt >= tileoff[gg] && mt < tileoff[gg + 1]) { g = gg; gto = tileoff[gg]; }
    if (g < 0) return;
    int goff = off[g], cnt = off[g + 1] - goff;
    int row0 = (mt - gto) * BM;
    const u16* Wb = Wt1 + (size_t)g * (ID * HD);
    int n0 = bx * BN;
    int tid = threadIdx.x, lane = tid & 63, w = tid >> 6;

    int rr, qq; decode_slot(tid, rr, qq);      // issue1 = rows rr+64, same quad
    int ra0 = row0 + rr;     ra0 = (ra0 < cnt) ? ra0 : (cnt - 1);
    int ra1 = row0 + rr + 64; ra1 = (ra1 < cnt) ? ra1 : (cnt - 1);
    const u16* pa0 = xb + (size_t)list[goff + ra0] * HD + qq * 8;
    const u16* pa1 = xb + (size_t)list[goff + ra1] * HD + qq * 8;
    const u16* pb0 = Wb + (size_t)(n0 + rr) * HD + qq * 8;
    const u16* pb1 = Wb + (size_t)(n0 + rr + 64) * HD + qq * 8;

    int wr = w >> 1, wc = w & 1;
    int lr = lane & 15, q2 = lane >> 4;
    int cp = (((lr & 1) << 2) | q2) ^ (lr >> 1);
    int offA = (wr * 32 + (lr >> 1)) * 64 + cp * 8;
    int offB = (wc * 32 + (lr >> 1)) * 64 + cp * 8;
    f32x4 acc[4][4] = {};

    auto stage = [&](int b) {
        u16* A = S + b * 8192;
        u16* B = A + 4096;
        gl_lds16(pa0, A + tid * 8);        pa0 += BK;
        gl_lds16(pa1, A + 2048 + tid * 8); pa1 += BK;
        gl_lds16(pb0, B + tid * 8);        pb0 += BK;
        gl_lds16(pb1, B + 2048 + tid * 8); pb1 += BK;
    };
    auto compute = [&](int b) {
        const u16* A = S + b * 8192;
        const u16* B = A + 4096;
        bf16x8 a[4], bb[4];
#pragma unroll
        for (int f = 0; f < 4; f++) {
            a[f]  = __builtin_bit_cast(bf16x8, *(const uint4*)&A[offA + f * 512]);
            bb[f] = __builtin_bit_cast(bf16x8, *(const uint4*)&B[offB + f * 512]);
        }
        __builtin_amdgcn_s_setprio(1);
#pragma unroll
        for (int mf = 0; mf < 4; mf++)
#pragma unroll
            for (int nf = 0; nf < 4; nf++)
                acc[mf][nf] = __builtin_amdgcn_mfma_f32_16x16x32_bf16(a[mf], bb[nf], acc[mf][nf], 0, 0, 0);
        __builtin_amdgcn_s_setprio(0);
    };

    stage(0);
    int cur = 0;
    for (int t = 1; t < HD / BK; ++t) {   // 64 K-steps
        stage(cur ^ 1);
        asm volatile("s_waitcnt vmcnt(4)" ::: "memory");
        __builtin_amdgcn_s_barrier();
        compute(cur);
        asm volatile("s_waitcnt lgkmcnt(0)" ::: "memory");
        __builtin_amdgcn_s_barrier();
        cur ^= 1;
    }
    asm volatile("s_waitcnt vmcnt(0)" ::: "memory");
    __builtin_amdgcn_s_barrier();
    compute(cur);

    // epilogue: SiLU, store h1 with k-frag perm within each 64-col block
    int q4 = q2 * 4;
    int cl = ((lr >> 2) << 3) + (lr & 3);
#pragma unroll
    for (int mf = 0; mf < 4; mf++)
#pragma unroll
        for (int reg = 0; reg < 4; reg++) {
            int r = row0 + wr * 64 + mf * 16 + q4 + reg;
            if (r < cnt) {
                size_t rb = (size_t)(goff + r) * ID + n0 + wc * 64;
#pragma unroll
                for (int nf = 0; nf < 4; nf++) {
                    float v = acc[mf][nf][reg];
                    h1[rb + ((nf >> 1) << 5) + ((nf & 1) << 2) + cl] = f2bf(v / (1.f + __expf(-v)));
                }
            }
        }
}

// ---------------- fc2: EO=1 -> eo[slot] bf16 stores; EO=0 -> atomic y -------
template <bool EO>
__global__ __launch_bounds__(256, 5) void fc2_kernel(
    const u16* __restrict__ h1, const u16* __restrict__ Wt2,
    const int* __restrict__ off, const int* __restrict__ tileoff,
    const int* __restrict__ list, const float* __restrict__ wgt,
    u16* __restrict__ eo, float* __restrict__ y) {
    __shared__ u16 S[16384];
    int nwg = gridDim.x * gridDim.y;            // 16*104 = 1664, %8==0
    int orig = blockIdx.y * gridDim.x + blockIdx.x;
    int wg = (orig & 7) * (nwg >> 3) + (orig >> 3);
    int bx = wg % gridDim.x, mt = wg / gridDim.x;

    int g = -1, gto = 0;
#pragma unroll
    for (int gg = 0; gg < NG; gg++)
        if (mt >= tileoff[gg] && mt < tileoff[gg + 1]) { g = gg; gto = tileoff[gg]; }
    if (g < 0) return;
    int goff = off[g], cnt = off[g + 1] - goff;
    int row0 = (mt - gto) * BM;
    const u16* Wb = Wt2 + (size_t)g * (ID * HD);
    int n0 = bx * BN;
    int tid = threadIdx.x, lane = tid & 63, w = tid >> 6;

    int rr, qq; decode_slot(tid, rr, qq);
    int ra0 = row0 + rr;      ra0 = (ra0 < cnt) ? ra0 : (cnt - 1);
    int ra1 = row0 + rr + 64; ra1 = (ra1 < cnt) ? ra1 : (cnt - 1);
    const u16* pa0 = h1 + (size_t)(goff + ra0) * ID + qq * 8;
    const u16* pa1 = h1 + (size_t)(goff + ra1) * ID + qq * 8;
    const u16* pb0 = Wb + (size_t)(n0 + rr) * ID + qq * 8;
    const u16* pb1 = Wb + (size_t)(n0 + rr + 64) * ID + qq * 8;

    int wr = w >> 1, wc = w & 1;
    int lr = lane & 15, q2 = lane >> 4;
    int cp = (((lr & 1) << 2) | q2) ^ (lr >> 1);
    int offA = (wr * 32 + (lr >> 1)) * 64 + cp * 8;
    int offB = (wc * 32 + (lr >> 1)) * 64 + cp * 8;
    f32x4 acc[4][4] = {};

    auto stage = [&](int b) {
        u16* A = S + b * 8192;
        u16* B = A + 4096;
        gl_lds16(pa0, A + tid * 8);        pa0 += BK;
        gl_lds16(pa1, A + 2048 + tid * 8); pa1 += BK;
        gl_lds16(pb0, B + tid * 8);        pb0 += BK;
        gl_lds16(pb1, B + 2048 + tid * 8); pb1 += BK;
    };
    auto compute = [&](int b) {
        const u16* A = S + b * 8192;
        const u16* B = A + 4096;
        bf16x8 a[4], bb[4];
#pragma unroll
        for (int f = 0; f < 4; f++) {
            a[f]  = __builtin_bit_cast(bf16x8, *(const uint4*)&A[offA + f * 512]);
            bb[f] = __builtin_bit_cast(bf16x8, *(const uint4*)&B[offB + f * 512]);
        }
        __builtin_amdgcn_s_setprio(1);
#pragma unroll
        for (int mf = 0; mf < 4; mf++)
#pragma unroll
            for (int nf = 0; nf < 4; nf++)
                acc[mf][nf] = __builtin_amdgcn_mfma_f32_16x16x32_bf16(a[mf], bb[nf], acc[mf][nf], 0, 0, 0);
        __builtin_amdgcn_s_setprio(0);
    };

    stage(0);
    int cur = 0;
    for (int t = 1; t < ID / BK; ++t) {   // 44 K-steps
        stage(cur ^ 1);
        asm volatile("s_waitcnt vmcnt(4)" ::: "memory");
        __builtin_amdgcn_s_barrier();
        compute(cur);
        asm volatile("s_waitcnt lgkmcnt(0)" ::: "memory");
        __builtin_amdgcn_s_barrier();
        cur ^= 1;
    }
    asm volatile("s_waitcnt vmcnt(0)" ::: "memory");
    __builtin_amdgcn_s_barrier();
    compute(cur);

    int q4 = q2 * 4;
#pragma unroll
    for (int mf = 0; mf < 4; mf++)
#pragma unroll
        for (int reg = 0; reg < 4; reg++) {
            int r = row0 + wr * 64 + mf * 16 + q4 + reg;
            if (r < cnt) {
                int slot = goff + r;
                if (EO) {
                    size_t rb = (size_t)slot * HD + n0 + wc * 64;
#pragma unroll
                    for (int nf = 0; nf < 4; nf++)
                        eo[rb + nf * 16 + lr] = f2bf(acc[mf][nf][reg]);
                } else {
                    int tok = list[slot];
                    float wv = wgt[slot];
                    float* yr = y + (size_t)tok * HD + n0 + wc * 64;
#pragma unroll
                    for (int nf = 0; nf < 4; nf++)
                        atomicAdd(yr + nf * 16 + lr, acc[mf][nf][reg] * wv);
                }
            }
        }
}

// ---------------- combine: y[t] = w0*eo[s0] + w1*eo[s1] + eo[shared] --------
__global__ __launch_bounds__(256) void combine_kernel(
    const u16* __restrict__ eo, const int* __restrict__ smap,
    const float* __restrict__ tkv, const int* __restrict__ off,
    float* __restrict__ y) {
    int idx = blockIdx.x * 256 + threadIdx.x;
    int t = idx >> 8;
    int cc = (idx & 255) << 3;
    int s0 = smap[t * 2 + 0], s1 = smap[t * 2 + 1];
    float w0 = tkv[t * 2 + 0], w1 = tkv[t * 2 + 1];
    int s2 = off[NE] + t;
    uint4 A = *(const uint4*)(eo + (size_t)s0 * HD + cc);
    uint4 B = *(const uint4*)(eo + (size_t)s1 * HD + cc);
    uint4 C = *(const uint4*)(eo + (size_t)s2 * HD + cc);
    float4 o0, o1;
    o0.x = w0 * bflo(A.x) + w1 * bflo(B.x) + bflo(C.x);
    o0.y = w0 * bfhi(A.x) + w1 * bfhi(B.x) + bfhi(C.x);
    o0.z = w0 * bflo(A.y) + w1 * bflo(B.y) + bflo(C.y);
    o0.w = w0 * bfhi(A.y) + w1 * bfhi(B.y) + bfhi(C.y);
    o1.x = w0 * bflo(A.z) + w1 * bflo(B.z) + bflo(C.z);
    o1.y = w0 * bfhi(A.z) + w1 * bfhi(B.z) + bfhi(C.z);
    o1.z = w0 * bflo(A.w) + w1 * bflo(B.w) + bflo(C.w);
    o1.w = w0 * bfhi(A.w) + w1 * bfhi(B.w) + bfhi(C.w);
    float* yr = y + (size_t)t * HD + cc;
    *(float4*)yr = o0;
    *(float4*)(yr + 4) = o1;
}

// ---------------- launch -----------------------------------------------------
extern "C" void kernel_launch(void* const* d_in, const int* in_sizes, int n_in,
                              void* d_out, int out_size, void* d_ws, size_t ws_size,
                              hipStream_t stream) {
    const float* x   = (const float*)d_in[0];
    const float* gw  = (const float*)d_in[1];
    const float* W1  = (const float*)d_in[2];
    const float* W2  = (const float*)d_in[3];
    const float* Ws1 = (const float*)d_in[4];
    const float* Ws2 = (const float*)d_in[5];
    float* out = (float*)d_out;

    char* ws = (char*)d_ws;
    int*   counts  = (int*)(ws + 0);
    int*   cursor  = (int*)(ws + 64);
    int*   off     = (int*)(ws + 128);
    int*   tileoff = (int*)(ws + 192);
    float* imp     = (float*)(ws + 256);
    int*   tki     = (int*)(ws + 320);                    // becomes slot-map after scatter
    float* tkv     = (float*)(ws + 33088);
    int*   list    = (int*)(ws + 65856);
    float* wgt     = (float*)(ws + 115008);
    // big regions (bytes):
    //   xb  @ 164352        : 16,777,216
    //   Wt1 @ 16,941,568    : 51,904,512   (9 x 1408 x 2048 bf16)
    //   h1  @ 68,846,080    : 34,603,008   (12288 x 1408 bf16, perm'd cols)
    //   Wt2 @ 164352 (aliases xb+Wt1 after fc1) : 51,904,512
    //   eo  @ 103,449,088   : 50,331,648   (12288 x 2048 bf16) -- only if ws allows
    u16* xb  = (u16*)(ws + 164352);
    u16* wt1 = (u16*)(ws + 16941568ULL);
    u16* h1  = (u16*)(ws + 68846080ULL);
    u16* wt2 = (u16*)(ws + 164352);
    u16* eo  = (u16*)(ws + 103449088ULL);
    const bool use_eo = (ws_size >= 153780736ULL);

    if (!use_eo)
        hipMemsetAsync(d_out, 0, (size_t)out_size * sizeof(float), stream);
    hipMemsetAsync(d_ws, 0, 320, stream);

    router_kernel<<<NT / 4, 256, 0, stream>>>(x, gw, counts, imp, tki, tkv, xb);
    prep_kernel<<<1, 64, 0, stream>>>(counts, imp, off, tileoff, out + (size_t)NT * HD);
    scatter_kernel<<<NT / 256, 256, 0, stream>>>(tki, tkv, off, cursor, list, wgt);

    transw_kernel<<<dim3(ID / 64, HD / 64, NG), 256, 0, stream>>>(W1, Ws1, wt1, HD, ID);

    fc1_kernel<<<dim3(ID / BN, MT_MAX), 256, 0, stream>>>(xb, wt1, off, tileoff, list, h1);

    // Wt2 overwrites xb/Wt1 (both dead after fc1); stream order guarantees safety
    transw_kernel<<<dim3(HD / 64, ID / 64, NG), 256, 0, stream>>>(W2, Ws2, wt2, ID, HD);

    if (use_eo) {
        fc2_kernel<true><<<dim3(HD / BN, MT_MAX), 256, 0, stream>>>(
            h1, wt2, off, tileoff, list, wgt, eo, out);
        combine_kernel<<<NT, 256, 0, stream>>>(eo, tki, tkv, off, out);
    } else {
        fc2_kernel<false><<<dim3(HD / BN, MT_MAX), 256, 0, stream>>>(
            h1, wt2, off, tileoff, list, wgt, eo, out);
    }
}

// Round 8
// 342.824 us; speedup vs baseline: 1.6564x; 1.6564x over previous
//
#include <hip/hip_runtime.h>
#include <hip/hip_bf16.h>

#define NT 4096          // B*T tokens
#define HD 2048          // hidden
#define NE 8             // experts
#define TOPK 2
#define ID 1408          // intermediate
#define NG 9             // 8 experts + shared
#define BM 128
#define BN 64
#define BK 64
#define MT_MAX 104       // max sum of ceil(cnt/128) over groups (<=72) + 32 shared

typedef unsigned short u16;
typedef unsigned int u32;
typedef unsigned long long u64;
typedef __attribute__((ext_vector_type(8))) short bf16x8;
typedef __attribute__((ext_vector_type(4))) float f32x4;

__device__ __forceinline__ u16 f2bf(float f) {
    u32 u = __builtin_bit_cast(u32, f);
    u += 0x7FFFu + ((u >> 16) & 1u);   // round-to-nearest-even
    return (u16)(u >> 16);
}
__device__ __forceinline__ float bflo(u32 v) { return __builtin_bit_cast(float, v << 16); }
__device__ __forceinline__ float bfhi(u32 v) { return __builtin_bit_cast(float, v & 0xffff0000u); }

// async global->LDS, 16B per lane; lds base must be wave-uniform
typedef __attribute__((address_space(1))) const void gas_void;
typedef __attribute__((address_space(3))) void las_void;
__device__ __forceinline__ void gl_lds16(const void* g, void* l) {
    __builtin_amdgcn_global_load_lds((gas_void*)(u64)g, (las_void*)(u32)(u64)l, 16, 0, 0);
}

// ---------------- router + x->bf16 perm convert (fused) ---------------------
__global__ void router_kernel(const float* __restrict__ x, const float* __restrict__ gw,
                              int* __restrict__ counts, float* __restrict__ imp,
                              int* __restrict__ tki, float* __restrict__ tkv,
                              u16* __restrict__ xb) {
    __shared__ float s_imp[NE];
    __shared__ int s_cnt[NE];
    if (threadIdx.x < NE) { s_imp[threadIdx.x] = 0.f; s_cnt[threadIdx.x] = 0; }
    int w = threadIdx.x >> 6, lane = threadIdx.x & 63;
    int t = blockIdx.x * 4 + w;
    float acc[NE];
#pragma unroll
    for (int e = 0; e < NE; e++) acc[e] = 0.f;
    const float* xr = x + (size_t)t * HD;
    u16* xw = xb + (size_t)t * HD;
#pragma unroll
    for (int i = 0; i < 4; i++) {
        int cc = i * 64 + lane;
        int b64 = cc >> 3, j = cc & 7, h = j >> 2, q = j & 3;
        int k0 = b64 * 64 + h * 32 + q * 4;
        float4 v0 = *(const float4*)(xr + k0);
        float4 v1 = *(const float4*)(xr + k0 + 16);
#pragma unroll
        for (int e = 0; e < NE; e++) {
            const float* gp = gw + e * HD + k0;
            float4 g0 = *(const float4*)(gp);
            float4 g1 = *(const float4*)(gp + 16);
            acc[e] += v0.x * g0.x + v0.y * g0.y + v0.z * g0.z + v0.w * g0.w
                    + v1.x * g1.x + v1.y * g1.y + v1.z * g1.z + v1.w * g1.w;
        }
        ushort4 o0, o1;
        o0.x = f2bf(v0.x); o0.y = f2bf(v0.y); o0.z = f2bf(v0.z); o0.w = f2bf(v0.w);
        o1.x = f2bf(v1.x); o1.y = f2bf(v1.y); o1.z = f2bf(v1.z); o1.w = f2bf(v1.w);
        uint4 o;
        o.x = (u32)o0.x | ((u32)o0.y << 16); o.y = (u32)o0.z | ((u32)o0.w << 16);
        o.z = (u32)o1.x | ((u32)o1.y << 16); o.w = (u32)o1.z | ((u32)o1.w << 16);
        *(uint4*)(xw + b64 * 64 + j * 8) = o;
    }
#pragma unroll
    for (int e = 0; e < NE; e++) {
#pragma unroll
        for (int o = 32; o >= 1; o >>= 1) acc[e] += __shfl_xor(acc[e], o, 64);
    }
    __syncthreads();
    if (lane == 0) {
        float mx = acc[0];
        for (int e = 1; e < NE; e++) mx = fmaxf(mx, acc[e]);
        float p[NE], sum = 0.f;
        for (int e = 0; e < NE; e++) { p[e] = expf(acc[e] - mx); sum += p[e]; }
        float inv = 1.f / sum;
        for (int e = 0; e < NE; e++) p[e] *= inv;
        int i1 = 0;
        for (int e = 1; e < NE; e++) if (p[e] > p[i1]) i1 = e;
        int i2 = (i1 == 0) ? 1 : 0;
        for (int e = 0; e < NE; e++) if (e != i1 && p[e] > p[i2]) i2 = e;
        tki[t * 2 + 0] = i1; tkv[t * 2 + 0] = p[i1];
        tki[t * 2 + 1] = i2; tkv[t * 2 + 1] = p[i2];
        for (int e = 0; e < NE; e++) atomicAdd(&s_imp[e], p[e]);
        atomicAdd(&s_cnt[i1], 1); atomicAdd(&s_cnt[i2], 1);
    }
    __syncthreads();
    if (threadIdx.x < NE) {
        atomicAdd(&imp[threadIdx.x], s_imp[threadIdx.x]);
        atomicAdd(&counts[threadIdx.x], s_cnt[threadIdx.x]);
    }
}

// ---------------- prep -------------------------------------------------------
__global__ void prep_kernel(const int* __restrict__ counts, const float* __restrict__ imp,
                            int* __restrict__ off, int* __restrict__ tileoff,
                            float* __restrict__ out_aux) {
    if (threadIdx.x == 0 && blockIdx.x == 0) {
        int o = 0, to = 0;
        for (int g = 0; g < NG; g++) {
            int c = (g < NE) ? counts[g] : NT;
            off[g] = o; tileoff[g] = to;
            o += c; to += (c + BM - 1) / BM;
        }
        off[NG] = o; tileoff[NG] = to;
        float aux = 0.f;
        for (int e = 0; e < NE; e++)
            aux += (imp[e] / (float)NT) * ((float)counts[e] / (float)(NT * TOPK));
        *out_aux = aux * (float)NE;
    }
}

// ---------------- scatter: token lists + slot map (overwrites tki) ----------
__global__ void scatter_kernel(int* __restrict__ tki, const float* __restrict__ tkv,
                               const int* __restrict__ off, int* __restrict__ cursor,
                               int* __restrict__ list, float* __restrict__ wgt) {
    int t = blockIdx.x * blockDim.x + threadIdx.x;
    if (t >= NT) return;
#pragma unroll
    for (int k = 0; k < TOPK; k++) {
        int e = tki[t * 2 + k];
        int pos = atomicAdd(&cursor[e], 1);
        int s = off[e] + pos;
        list[s] = t;
        wgt[s] = tkv[t * 2 + k];
        tki[t * 2 + k] = s;
    }
    list[off[NE] + t] = t;
    wgt[off[NE] + t] = 1.0f;
}

// ---------------- transpose+convert weights (experts + shared in one grid) --
__global__ void transw_kernel(const float* __restrict__ W, const float* __restrict__ Wsh,
                              u16* __restrict__ dst, int K, int N) {
    int e = blockIdx.z;
    const float* src = (e < NE) ? (W + (size_t)e * K * N) : Wsh;
    dst += (size_t)e * N * K;
    int k0 = blockIdx.y * 64, n0 = blockIdx.x * 64;
    __shared__ u16 Lt[64][68];
    int tid = threadIdx.x;
#pragma unroll
    for (int i = 0; i < 4; i++) {
        int idx = i * 256 + tid;
        int kl = idx >> 4, nq = (idx & 15) * 4;
        float4 v = *(const float4*)(src + (size_t)(k0 + kl) * N + n0 + nq);
        Lt[nq + 0][kl] = f2bf(v.x); Lt[nq + 1][kl] = f2bf(v.y);
        Lt[nq + 2][kl] = f2bf(v.z); Lt[nq + 3][kl] = f2bf(v.w);
    }
    __syncthreads();
#pragma unroll
    for (int c2 = 0; c2 < 2; c2++) {
        int cid = tid * 2 + c2;
        int nr = cid >> 3, j = cid & 7;
        int h = j >> 2, q = j & 3;
        int kb = h * 32 + q * 4;
        uint2 lo = *(const uint2*)&Lt[nr][kb];
        uint2 hi = *(const uint2*)&Lt[nr][kb + 16];
        uint4 o; o.x = lo.x; o.y = lo.y; o.z = hi.x; o.w = hi.y;
        *(uint4*)(dst + (size_t)(n0 + nr) * K + k0 + j * 8) = o;
    }
}

// ---------------- fc1: h1 = SiLU(xb_gathered @ Wt1_g^T), perm'd bf16 out ----
// Round-6 geometry (128x64 tile, BK=64, XOR-swizzle) + 3-buffer depth-2
// prefetch: issue tile t+2, wait vmcnt(12) (= tile t landed), compute t.
__global__ __launch_bounds__(256) void fc1_kernel(
    const u16* __restrict__ xb, const u16* __restrict__ Wt1,
    const int* __restrict__ off, const int* __restrict__ tileoff,
    const int* __restrict__ list, u16* __restrict__ h1) {
    __shared__ u16 S[3 * 12288];   // per buffer: A 128x64 (16KB) + B 64x64 (8KB)
    int nwg = gridDim.x * gridDim.y;           // 22*104 = 2288, %8==0
    int orig = blockIdx.y * gridDim.x + blockIdx.x;
    int wg = (orig & 7) * (nwg >> 3) + (orig >> 3);
    int bx = wg % gridDim.x, mt = wg / gridDim.x;

    int g = -1, gto = 0;
#pragma unroll
    for (int gg = 0; gg < NG; gg++)
        if (mt >= tileoff[gg] && mt < tileoff[gg + 1]) { g = gg; gto = tileoff[gg]; }
    if (g < 0) return;
    int goff = off[g], cnt = off[g + 1] - goff;
    int row0 = (mt - gto) * BM;
    const u16* Wb = Wt1 + (size_t)g * (ID * HD);
    int n0 = bx * BN;
    int tid = threadIdx.x, lane = tid & 63, w = tid >> 6;
    int lm = lane >> 3;
    int lc = (((lane & 7) ^ lm) << 3);          // swizzled source chunk
    const u16* pa[4]; const u16* pb[2];
#pragma unroll
    for (int i = 0; i < 4; i++) {
        int c = i * 4 + w;
        int r = row0 + c * 8 + lm;
        r = (r < cnt) ? r : (cnt - 1);
        pa[i] = xb + (size_t)list[goff + r] * HD + lc;
    }
#pragma unroll
    for (int i = 0; i < 2; i++) {
        int c = i * 4 + w;
        pb[i] = Wb + (size_t)(n0 + c * 8 + lm) * HD + lc;
    }
    int wr = w >> 1, wc = w & 1;
    int lr = lane & 15, l7 = lane & 7, q2 = lane >> 4;
    f32x4 acc[4][2] = {};

    auto stage = [&](int b) {
        u16* A = S + b * 12288;
        u16* B = A + 8192;
#pragma unroll
        for (int i = 0; i < 4; i++) { gl_lds16(pa[i], A + (i * 4 + w) * 512); pa[i] += BK; }
#pragma unroll
        for (int i = 0; i < 2; i++) { gl_lds16(pb[i], B + (i * 4 + w) * 512); pb[i] += BK; }
    };
    auto compute = [&](int b) {
        const u16* A = S + b * 12288;
        const u16* B = A + 8192;
#pragma unroll
        for (int kc = 0; kc < 8; kc += 4) {
            int slot = ((kc + q2) ^ l7) << 3;
            bf16x8 a[4], bb[2];
#pragma unroll
            for (int f = 0; f < 4; f++)
                a[f] = __builtin_bit_cast(bf16x8, *(const uint4*)&A[(wr * 64 + f * 16 + lr) * BK + slot]);
#pragma unroll
            for (int f = 0; f < 2; f++)
                bb[f] = __builtin_bit_cast(bf16x8, *(const uint4*)&B[(wc * 32 + f * 16 + lr) * BK + slot]);
            __builtin_amdgcn_s_setprio(1);
#pragma unroll
            for (int mf = 0; mf < 4; mf++)
#pragma unroll
                for (int nf = 0; nf < 2; nf++)
                    acc[mf][nf] = __builtin_amdgcn_mfma_f32_16x16x32_bf16(a[mf], bb[nf], acc[mf][nf], 0, 0, 0);
            __builtin_amdgcn_s_setprio(0);
        }
    };

    stage(0);
    stage(1);
    int cb = 0, sb = 2;
    for (int t = 0; t < HD / BK - 2; ++t) {   // 30 pipelined steps
        stage(sb);
        asm volatile("s_waitcnt vmcnt(12)" ::: "memory");   // tile t landed
        __builtin_amdgcn_s_barrier();
        compute(cb);
        asm volatile("s_waitcnt lgkmcnt(0)" ::: "memory");
        __builtin_amdgcn_s_barrier();                        // buf cb free to overwrite
        cb = (cb == 2) ? 0 : cb + 1;
        sb = (sb == 2) ? 0 : sb + 1;
    }
    asm volatile("s_waitcnt vmcnt(6)" ::: "memory");
    __builtin_amdgcn_s_barrier();
    compute(cb);
    cb = (cb == 2) ? 0 : cb + 1;
    asm volatile("s_waitcnt vmcnt(0)" ::: "memory");
    __builtin_amdgcn_s_barrier();
    compute(cb);

    // epilogue: SiLU, store h1 with k-frag perm within each 64-col block
    int q4 = q2 * 4;
    int cl = ((lr >> 2) << 3) + (lr & 3);
#pragma unroll
    for (int mf = 0; mf < 4; mf++)
#pragma unroll
        for (int reg = 0; reg < 4; reg++) {
            int r = row0 + wr * 64 + mf * 16 + q4 + reg;
            if (r < cnt) {
                size_t rb = (size_t)(goff + r) * ID + n0;
#pragma unroll
                for (int nf = 0; nf < 2; nf++) {
                    float v = acc[mf][nf][reg];
                    h1[rb + wc * 32 + (nf << 2) + cl] = f2bf(v / (1.f + __expf(-v)));
                }
            }
        }
}

// ---------------- fc2: EO=1 -> eo[slot] bf16 stores; EO=0 -> atomic y -------
template <bool EO>
__global__ __launch_bounds__(256) void fc2_kernel(
    const u16* __restrict__ h1, const u16* __restrict__ Wt2,
    const int* __restrict__ off, const int* __restrict__ tileoff,
    const int* __restrict__ list, const float* __restrict__ wgt,
    u16* __restrict__ eo, float* __restrict__ y) {
    __shared__ u16 S[3 * 12288];
    int nwg = gridDim.x * gridDim.y;            // 32*104 = 3328, %8==0
    int orig = blockIdx.y * gridDim.x + blockIdx.x;
    int wg = (orig & 7) * (nwg >> 3) + (orig >> 3);
    int bx = wg % gridDim.x, mt = wg / gridDim.x;

    int g = -1, gto = 0;
#pragma unroll
    for (int gg = 0; gg < NG; gg++)
        if (mt >= tileoff[gg] && mt < tileoff[gg + 1]) { g = gg; gto = tileoff[gg]; }
    if (g < 0) return;
    int goff = off[g], cnt = off[g + 1] - goff;
    int row0 = (mt - gto) * BM;
    const u16* Wb = Wt2 + (size_t)g * (ID * HD);
    int n0 = bx * BN;
    int tid = threadIdx.x, lane = tid & 63, w = tid >> 6;
    int lm = lane >> 3;
    int lc = (((lane & 7) ^ lm) << 3);
    const u16* pa[4]; const u16* pb[2];
#pragma unroll
    for (int i = 0; i < 4; i++) {
        int c = i * 4 + w;
        int r = row0 + c * 8 + lm;
        r = (r < cnt) ? r : (cnt - 1);
        pa[i] = h1 + (size_t)(goff + r) * ID + lc;           // slot-indexed, perm'd
    }
#pragma unroll
    for (int i = 0; i < 2; i++) {
        int c = i * 4 + w;
        pb[i] = Wb + (size_t)(n0 + c * 8 + lm) * ID + lc;    // perm'd weights
    }
    int wr = w >> 1, wc = w & 1;
    int lr = lane & 15, l7 = lane & 7, q2 = lane >> 4;
    f32x4 acc[4][2] = {};

    auto stage = [&](int b) {
        u16* A = S + b * 12288;
        u16* B = A + 8192;
#pragma unroll
        for (int i = 0; i < 4; i++) { gl_lds16(pa[i], A + (i * 4 + w) * 512); pa[i] += BK; }
#pragma unroll
        for (int i = 0; i < 2; i++) { gl_lds16(pb[i], B + (i * 4 + w) * 512); pb[i] += BK; }
    };
    auto compute = [&](int b) {
        const u16* A = S + b * 12288;
        const u16* B = A + 8192;
#pragma unroll
        for (int kc = 0; kc < 8; kc += 4) {
            int slot = ((kc + q2) ^ l7) << 3;
            bf16x8 a[4], bb[2];
#pragma unroll
            for (int f = 0; f < 4; f++)
                a[f] = __builtin_bit_cast(bf16x8, *(const uint4*)&A[(wr * 64 + f * 16 + lr) * BK + slot]);
#pragma unroll
            for (int f = 0; f < 2; f++)
                bb[f] = __builtin_bit_cast(bf16x8, *(const uint4*)&B[(wc * 32 + f * 16 + lr) * BK + slot]);
            __builtin_amdgcn_s_setprio(1);
#pragma unroll
            for (int mf = 0; mf < 4; mf++)
#pragma unroll
                for (int nf = 0; nf < 2; nf++)
                    acc[mf][nf] = __builtin_amdgcn_mfma_f32_16x16x32_bf16(a[mf], bb[nf], acc[mf][nf], 0, 0, 0);
            __builtin_amdgcn_s_setprio(0);
        }
    };

    stage(0);
    stage(1);
    int cb = 0, sb = 2;
    for (int t = 0; t < ID / BK - 2; ++t) {   // 20 pipelined steps
        stage(sb);
        asm volatile("s_waitcnt vmcnt(12)" ::: "memory");
        __builtin_amdgcn_s_barrier();
        compute(cb);
        asm volatile("s_waitcnt lgkmcnt(0)" ::: "memory");
        __builtin_amdgcn_s_barrier();
        cb = (cb == 2) ? 0 : cb + 1;
        sb = (sb == 2) ? 0 : sb + 1;
    }
    asm volatile("s_waitcnt vmcnt(6)" ::: "memory");
    __builtin_amdgcn_s_barrier();
    compute(cb);
    cb = (cb == 2) ? 0 : cb + 1;
    asm volatile("s_waitcnt vmcnt(0)" ::: "memory");
    __builtin_amdgcn_s_barrier();
    compute(cb);

    int q4 = q2 * 4;
#pragma unroll
    for (int mf = 0; mf < 4; mf++)
#pragma unroll
        for (int reg = 0; reg < 4; reg++) {
            int r = row0 + wr * 64 + mf * 16 + q4 + reg;
            if (r < cnt) {
                int slot = goff + r;
                if (EO) {
                    size_t rb = (size_t)slot * HD + n0 + wc * 32;
#pragma unroll
                    for (int nf = 0; nf < 2; nf++)
                        eo[rb + nf * 16 + lr] = f2bf(acc[mf][nf][reg]);
                } else {
                    int tok = list[slot];
                    float wv = wgt[slot];
                    float* yr = y + (size_t)tok * HD + n0 + wc * 32;
#pragma unroll
                    for (int nf = 0; nf < 2; nf++)
                        atomicAdd(yr + nf * 16 + lr, acc[mf][nf][reg] * wv);
                }
            }
        }
}

// ---------------- combine: y[t] = w0*eo[s0] + w1*eo[s1] + eo[shared] --------
__global__ __launch_bounds__(256) void combine_kernel(
    const u16* __restrict__ eo, const int* __restrict__ smap,
    const float* __restrict__ tkv, const int* __restrict__ off,
    float* __restrict__ y) {
    int idx = blockIdx.x * 256 + threadIdx.x;
    int t = idx >> 8;
    int cc = (idx & 255) << 3;
    int s0 = smap[t * 2 + 0], s1 = smap[t * 2 + 1];
    float w0 = tkv[t * 2 + 0], w1 = tkv[t * 2 + 1];
    int s2 = off[NE] + t;
    uint4 A = *(const uint4*)(eo + (size_t)s0 * HD + cc);
    uint4 B = *(const uint4*)(eo + (size_t)s1 * HD + cc);
    uint4 C = *(const uint4*)(eo + (size_t)s2 * HD + cc);
    float4 o0, o1;
    o0.x = w0 * bflo(A.x) + w1 * bflo(B.x) + bflo(C.x);
    o0.y = w0 * bfhi(A.x) + w1 * bfhi(B.x) + bfhi(C.x);
    o0.z = w0 * bflo(A.y) + w1 * bflo(B.y) + bflo(C.y);
    o0.w = w0 * bfhi(A.y) + w1 * bfhi(B.y) + bfhi(C.y);
    o1.x = w0 * bflo(A.z) + w1 * bflo(B.z) + bflo(C.z);
    o1.y = w0 * bfhi(A.z) + w1 * bfhi(B.z) + bfhi(C.z);
    o1.z = w0 * bflo(A.w) + w1 * bflo(B.w) + bflo(C.w);
    o1.w = w0 * bfhi(A.w) + w1 * bfhi(B.w) + bfhi(C.w);
    float* yr = y + (size_t)t * HD + cc;
    *(float4*)yr = o0;
    *(float4*)(yr + 4) = o1;
}

// ---------------- launch -----------------------------------------------------
extern "C" void kernel_launch(void* const* d_in, const int* in_sizes, int n_in,
                              void* d_out, int out_size, void* d_ws, size_t ws_size,
                              hipStream_t stream) {
    const float* x   = (const float*)d_in[0];
    const float* gw  = (const float*)d_in[1];
    const float* W1  = (const float*)d_in[2];
    const float* W2  = (const float*)d_in[3];
    const float* Ws1 = (const float*)d_in[4];
    const float* Ws2 = (const float*)d_in[5];
    float* out = (float*)d_out;

    char* ws = (char*)d_ws;
    int*   counts  = (int*)(ws + 0);
    int*   cursor  = (int*)(ws + 64);
    int*   off     = (int*)(ws + 128);
    int*   tileoff = (int*)(ws + 192);
    float* imp     = (float*)(ws + 256);
    int*   tki     = (int*)(ws + 320);                    // becomes slot-map after scatter
    float* tkv     = (float*)(ws + 33088);
    int*   list    = (int*)(ws + 65856);
    float* wgt     = (float*)(ws + 115008);
    // big regions (bytes):
    //   xb  @ 164352        : 16,777,216
    //   Wt1 @ 16,941,568    : 51,904,512   (9 x 1408 x 2048 bf16)
    //   h1  @ 68,846,080    : 34,603,008   (12288 x 1408 bf16, perm'd cols)
    //   Wt2 @ 164352 (aliases xb+Wt1 after fc1) : 51,904,512
    //   eo  @ 103,449,088   : 50,331,648   (12288 x 2048 bf16) -- only if ws allows
    u16* xb  = (u16*)(ws + 164352);
    u16* wt1 = (u16*)(ws + 16941568ULL);
    u16* h1  = (u16*)(ws + 68846080ULL);
    u16* wt2 = (u16*)(ws + 164352);
    u16* eo  = (u16*)(ws + 103449088ULL);
    const bool use_eo = (ws_size >= 153780736ULL);

    if (!use_eo)
        hipMemsetAsync(d_out, 0, (size_t)out_size * sizeof(float), stream);
    hipMemsetAsync(d_ws, 0, 320, stream);

    router_kernel<<<NT / 4, 256, 0, stream>>>(x, gw, counts, imp, tki, tkv, xb);
    prep_kernel<<<1, 64, 0, stream>>>(counts, imp, off, tileoff, out + (size_t)NT * HD);
    scatter_kernel<<<NT / 256, 256, 0, stream>>>(tki, tkv, off, cursor, list, wgt);

    transw_kernel<<<dim3(ID / 64, HD / 64, NG), 256, 0, stream>>>(W1, Ws1, wt1, HD, ID);

    fc1_kernel<<<dim3(ID / BN, MT_MAX), 256, 0, stream>>>(xb, wt1, off, tileoff, list, h1);

    // Wt2 overwrites xb/Wt1 (both dead after fc1); stream order guarantees safety
    transw_kernel<<<dim3(HD / 64, ID / 64, NG), 256, 0, stream>>>(W2, Ws2, wt2, ID, HD);

    if (use_eo) {
        fc2_kernel<true><<<dim3(HD / BN, MT_MAX), 256, 0, stream>>>(
            h1, wt2, off, tileoff, list, wgt, eo, out);
        combine_kernel<<<NT, 256, 0, stream>>>(eo, tki, tkv, off, out);
    } else {
        fc2_kernel<false><<<dim3(HD / BN, MT_MAX), 256, 0, stream>>>(
            h1, wt2, off, tileoff, list, wgt, eo, out);
    }
}

// Round 9
// 341.465 us; speedup vs baseline: 1.6630x; 1.0040x over previous
//
#include <hip/hip_runtime.h>
#include <hip/hip_bf16.h>

#define NT 4096          // B*T tokens
#define HD 2048          // hidden
#define NE 8             // experts
#define TOPK 2
#define ID 1408          // intermediate
#define NG 9             // 8 experts + shared
#define BM 256
#define BN 128
#define BK 64
#define MT_MAX 56        // max sum ceil(cnt/256) (<=40) + 16 shared

typedef unsigned short u16;
typedef unsigned int u32;
typedef unsigned long long u64;
typedef __attribute__((ext_vector_type(8))) short bf16x8;
typedef __attribute__((ext_vector_type(4))) float f32x4;

__device__ __forceinline__ u16 f2bf(float f) {
    u32 u = __builtin_bit_cast(u32, f);
    u += 0x7FFFu + ((u >> 16) & 1u);   // round-to-nearest-even
    return (u16)(u >> 16);
}
__device__ __forceinline__ float bflo(u32 v) { return __builtin_bit_cast(float, v << 16); }
__device__ __forceinline__ float bfhi(u32 v) { return __builtin_bit_cast(float, v & 0xffff0000u); }

// async global->LDS, 16B per lane; lds base must be wave-uniform
typedef __attribute__((address_space(1))) const void gas_void;
typedef __attribute__((address_space(3))) void las_void;
__device__ __forceinline__ void gl_lds16(const void* g, void* l) {
    __builtin_amdgcn_global_load_lds((gas_void*)(u64)g, (las_void*)(u32)(u64)l, 16, 0, 0);
}

// ---------------- router + x->bf16 perm convert (fused) ---------------------
__global__ void router_kernel(const float* __restrict__ x, const float* __restrict__ gw,
                              int* __restrict__ counts, float* __restrict__ imp,
                              int* __restrict__ tki, float* __restrict__ tkv,
                              u16* __restrict__ xb) {
    __shared__ float s_imp[NE];
    __shared__ int s_cnt[NE];
    if (threadIdx.x < NE) { s_imp[threadIdx.x] = 0.f; s_cnt[threadIdx.x] = 0; }
    int w = threadIdx.x >> 6, lane = threadIdx.x & 63;
    int t = blockIdx.x * 4 + w;
    float acc[NE];
#pragma unroll
    for (int e = 0; e < NE; e++) acc[e] = 0.f;
    const float* xr = x + (size_t)t * HD;
    u16* xw = xb + (size_t)t * HD;
#pragma unroll
    for (int i = 0; i < 4; i++) {
        int cc = i * 64 + lane;
        int b64 = cc >> 3, j = cc & 7, h = j >> 2, q = j & 3;
        int k0 = b64 * 64 + h * 32 + q * 4;
        float4 v0 = *(const float4*)(xr + k0);
        float4 v1 = *(const float4*)(xr + k0 + 16);
#pragma unroll
        for (int e = 0; e < NE; e++) {
            const float* gp = gw + e * HD + k0;
            float4 g0 = *(const float4*)(gp);
            float4 g1 = *(const float4*)(gp + 16);
            acc[e] += v0.x * g0.x + v0.y * g0.y + v0.z * g0.z + v0.w * g0.w
                    + v1.x * g1.x + v1.y * g1.y + v1.z * g1.z + v1.w * g1.w;
        }
        ushort4 o0, o1;
        o0.x = f2bf(v0.x); o0.y = f2bf(v0.y); o0.z = f2bf(v0.z); o0.w = f2bf(v0.w);
        o1.x = f2bf(v1.x); o1.y = f2bf(v1.y); o1.z = f2bf(v1.z); o1.w = f2bf(v1.w);
        uint4 o;
        o.x = (u32)o0.x | ((u32)o0.y << 16); o.y = (u32)o0.z | ((u32)o0.w << 16);
        o.z = (u32)o1.x | ((u32)o1.y << 16); o.w = (u32)o1.z | ((u32)o1.w << 16);
        *(uint4*)(xw + b64 * 64 + j * 8) = o;
    }
#pragma unroll
    for (int e = 0; e < NE; e++) {
#pragma unroll
        for (int o = 32; o >= 1; o >>= 1) acc[e] += __shfl_xor(acc[e], o, 64);
    }
    __syncthreads();
    if (lane == 0) {
        float mx = acc[0];
        for (int e = 1; e < NE; e++) mx = fmaxf(mx, acc[e]);
        float p[NE], sum = 0.f;
        for (int e = 0; e < NE; e++) { p[e] = expf(acc[e] - mx); sum += p[e]; }
        float inv = 1.f / sum;
        for (int e = 0; e < NE; e++) p[e] *= inv;
        int i1 = 0;
        for (int e = 1; e < NE; e++) if (p[e] > p[i1]) i1 = e;
        int i2 = (i1 == 0) ? 1 : 0;
        for (int e = 0; e < NE; e++) if (e != i1 && p[e] > p[i2]) i2 = e;
        tki[t * 2 + 0] = i1; tkv[t * 2 + 0] = p[i1];
        tki[t * 2 + 1] = i2; tkv[t * 2 + 1] = p[i2];
        for (int e = 0; e < NE; e++) atomicAdd(&s_imp[e], p[e]);
        atomicAdd(&s_cnt[i1], 1); atomicAdd(&s_cnt[i2], 1);
    }
    __syncthreads();
    if (threadIdx.x < NE) {
        atomicAdd(&imp[threadIdx.x], s_imp[threadIdx.x]);
        atomicAdd(&counts[threadIdx.x], s_cnt[threadIdx.x]);
    }
}

// ---------------- prep -------------------------------------------------------
__global__ void prep_kernel(const int* __restrict__ counts, const float* __restrict__ imp,
                            int* __restrict__ off, int* __restrict__ tileoff,
                            float* __restrict__ out_aux) {
    if (threadIdx.x == 0 && blockIdx.x == 0) {
        int o = 0, to = 0;
        for (int g = 0; g < NG; g++) {
            int c = (g < NE) ? counts[g] : NT;
            off[g] = o; tileoff[g] = to;
            o += c; to += (c + BM - 1) / BM;
        }
        off[NG] = o; tileoff[NG] = to;
        float aux = 0.f;
        for (int e = 0; e < NE; e++)
            aux += (imp[e] / (float)NT) * ((float)counts[e] / (float)(NT * TOPK));
        *out_aux = aux * (float)NE;
    }
}

// ---------------- scatter: token lists + slot map (overwrites tki) ----------
__global__ void scatter_kernel(int* __restrict__ tki, const float* __restrict__ tkv,
                               const int* __restrict__ off, int* __restrict__ cursor,
                               int* __restrict__ list, float* __restrict__ wgt) {
    int t = blockIdx.x * blockDim.x + threadIdx.x;
    if (t >= NT) return;
#pragma unroll
    for (int k = 0; k < TOPK; k++) {
        int e = tki[t * 2 + k];
        int pos = atomicAdd(&cursor[e], 1);
        int s = off[e] + pos;
        list[s] = t;
        wgt[s] = tkv[t * 2 + k];
        tki[t * 2 + k] = s;
    }
    list[off[NE] + t] = t;
    wgt[off[NE] + t] = 1.0f;
}

// ---------------- transpose+convert weights (experts + shared in one grid) --
__global__ void transw_kernel(const float* __restrict__ W, const float* __restrict__ Wsh,
                              u16* __restrict__ dst, int K, int N) {
    int e = blockIdx.z;
    const float* src = (e < NE) ? (W + (size_t)e * K * N) : Wsh;
    dst += (size_t)e * N * K;
    int k0 = blockIdx.y * 64, n0 = blockIdx.x * 64;
    __shared__ u16 Lt[64][68];
    int tid = threadIdx.x;
#pragma unroll
    for (int i = 0; i < 4; i++) {
        int idx = i * 256 + tid;
        int kl = idx >> 4, nq = (idx & 15) * 4;
        float4 v = *(const float4*)(src + (size_t)(k0 + kl) * N + n0 + nq);
        Lt[nq + 0][kl] = f2bf(v.x); Lt[nq + 1][kl] = f2bf(v.y);
        Lt[nq + 2][kl] = f2bf(v.z); Lt[nq + 3][kl] = f2bf(v.w);
    }
    __syncthreads();
#pragma unroll
    for (int c2 = 0; c2 < 2; c2++) {
        int cid = tid * 2 + c2;
        int nr = cid >> 3, j = cid & 7;
        int h = j >> 2, q = j & 3;
        int kb = h * 32 + q * 4;
        uint2 lo = *(const uint2*)&Lt[nr][kb];
        uint2 hi = *(const uint2*)&Lt[nr][kb + 16];
        uint4 o; o.x = lo.x; o.y = lo.y; o.z = hi.x; o.w = hi.y;
        *(uint4*)(dst + (size_t)(n0 + nr) * K + k0 + j * 8) = o;
    }
}

// ======================= 256x128 8-wave phase-split GEMM ====================
// 512 threads = 8 waves (4M x 2N), wave tile 64x64 (4x4 frags).
// LDS: 3 buffers x (A 256x64 = 32KB + B 128x64 = 16KB) = 144KB, 1 block/CU.
// Per K-tile: 2 phases; each = {8 ds_read_b128 + stage-part -> s_barrier ->
// setprio(1)+16 MFMA+setprio(0) -> s_barrier}; vmcnt(6) once per K-tile
// (t+1's 6 loads landed, t+2's 6 in flight). XOR-swizzle as round 3.

// ---------------- fc1: h1 = SiLU(xb_gathered @ Wt1_g^T), perm'd bf16 out ----
__global__ __launch_bounds__(512, 2) void fc1_kernel(
    const u16* __restrict__ xb, const u16* __restrict__ Wt1,
    const int* __restrict__ off, const int* __restrict__ tileoff,
    const int* __restrict__ list, u16* __restrict__ h1) {
    __shared__ u16 S[3 * 24576];
    int nwg = gridDim.x * gridDim.y;           // 11*56 = 616, %8==0
    int orig = blockIdx.y * gridDim.x + blockIdx.x;
    int wg = (orig & 7) * (nwg >> 3) + (orig >> 3);
    int bx = wg % gridDim.x, mt = wg / gridDim.x;

    int g = -1, gto = 0;
#pragma unroll
    for (int gg = 0; gg < NG; gg++)
        if (mt >= tileoff[gg] && mt < tileoff[gg + 1]) { g = gg; gto = tileoff[gg]; }
    if (g < 0) return;
    int goff = off[g], cnt = off[g + 1] - goff;
    int row0 = (mt - gto) * BM;
    const u16* Wb = Wt1 + (size_t)g * (ID * HD);
    int n0 = bx * BN;
    int tid = threadIdx.x, lane = tid & 63, w = tid >> 6;
    int lm = lane >> 3;
    int lc = (((lane & 7) ^ lm) << 3);          // swizzled source chunk
    const u16* pa[4]; const u16* pb[2];
#pragma unroll
    for (int i = 0; i < 4; i++) {
        int gi = i * 8 + w;                      // 32 groups of 8 rows = 256
        int r = row0 + gi * 8 + lm;
        r = (r < cnt) ? r : (cnt - 1);
        pa[i] = xb + (size_t)list[goff + r] * HD + lc;
    }
#pragma unroll
    for (int i = 0; i < 2; i++) {
        int gi = i * 8 + w;                      // 16 groups = 128 rows
        pb[i] = Wb + (size_t)(n0 + gi * 8 + lm) * HD + lc;
    }
    int wr = w >> 1, wc = w & 1;
    int lr = lane & 15, l7 = lane & 7, q2 = lane >> 4;
    f32x4 acc[4][4] = {};

    auto stageA = [&](int b) {
        u16* A = S + b * 24576;
#pragma unroll
        for (int i = 0; i < 4; i++) { gl_lds16(pa[i], A + (i * 8 + w) * 512); pa[i] += BK; }
    };
    auto stageB = [&](int b) {
        u16* B = S + b * 24576 + 16384;
#pragma unroll
        for (int i = 0; i < 2; i++) { gl_lds16(pb[i], B + (i * 8 + w) * 512); pb[i] += BK; }
    };

    const int NK = HD / BK;                      // 32
    stageA(0); stageB(0); stageA(1); stageB(1);
    asm volatile("s_waitcnt vmcnt(6)" ::: "memory");
    __builtin_amdgcn_s_barrier();
    int cb = 0, sb = 2;
    for (int t = 0; t < NK; ++t) {
        const u16* A = S + cb * 24576;
        const u16* B = A + 16384;
        bool pf = (t + 2 < NK);
#pragma unroll
        for (int ph = 0; ph < 2; ++ph) {         // phase = kc-half
            int slot = (((ph << 2) + q2) ^ l7) << 3;
            bf16x8 a[4], bb[4];
#pragma unroll
            for (int f = 0; f < 4; f++) {
                a[f]  = __builtin_bit_cast(bf16x8, *(const uint4*)&A[(wr * 64 + f * 16 + lr) * BK + slot]);
                bb[f] = __builtin_bit_cast(bf16x8, *(const uint4*)&B[(wc * 64 + f * 16 + lr) * BK + slot]);
            }
            if (pf) { if (ph == 0) stageA(sb); else stageB(sb); }
            __builtin_amdgcn_s_barrier();
            __builtin_amdgcn_s_setprio(1);
#pragma unroll
            for (int mf = 0; mf < 4; mf++)
#pragma unroll
                for (int nf = 0; nf < 4; nf++)
                    acc[mf][nf] = __builtin_amdgcn_mfma_f32_16x16x32_bf16(a[mf], bb[nf], acc[mf][nf], 0, 0, 0);
            __builtin_amdgcn_s_setprio(0);
            if (ph == 0) {
                __builtin_amdgcn_s_barrier();
            } else if (t + 1 < NK) {
                if (pf) asm volatile("s_waitcnt vmcnt(6)" ::: "memory");
                else    asm volatile("s_waitcnt vmcnt(0)" ::: "memory");
                __builtin_amdgcn_s_barrier();
            }
        }
        cb = (cb == 2) ? 0 : cb + 1;
        sb = (sb == 2) ? 0 : sb + 1;
    }

    // epilogue: SiLU, store h1 with k-frag perm within each 64-col block
    int q4 = q2 * 4;
    int cl = ((lr >> 2) << 3) + (lr & 3);
#pragma unroll
    for (int mf = 0; mf < 4; mf++)
#pragma unroll
        for (int reg = 0; reg < 4; reg++) {
            int r = row0 + wr * 64 + mf * 16 + q4 + reg;
            if (r < cnt) {
                size_t rb = (size_t)(goff + r) * ID + n0 + wc * 64;
#pragma unroll
                for (int nf = 0; nf < 4; nf++) {
                    float v = acc[mf][nf][reg];
                    h1[rb + ((nf >> 1) << 5) + ((nf & 1) << 2) + cl] = f2bf(v / (1.f + __expf(-v)));
                }
            }
        }
}

// ---------------- fc2: EO=1 -> eo[slot] bf16 stores; EO=0 -> atomic y -------
template <bool EO>
__global__ __launch_bounds__(512, 2) void fc2_kernel(
    const u16* __restrict__ h1, const u16* __restrict__ Wt2,
    const int* __restrict__ off, const int* __restrict__ tileoff,
    const int* __restrict__ list, const float* __restrict__ wgt,
    u16* __restrict__ eo, float* __restrict__ y) {
    __shared__ u16 S[3 * 24576];
    int nwg = gridDim.x * gridDim.y;            // 16*56 = 896, %8==0
    int orig = blockIdx.y * gridDim.x + blockIdx.x;
    int wg = (orig & 7) * (nwg >> 3) + (orig >> 3);
    int bx = wg % gridDim.x, mt = wg / gridDim.x;

    int g = -1, gto = 0;
#pragma unroll
    for (int gg = 0; gg < NG; gg++)
        if (mt >= tileoff[gg] && mt < tileoff[gg + 1]) { g = gg; gto = tileoff[gg]; }
    if (g < 0) return;
    int goff = off[g], cnt = off[g + 1] - goff;
    int row0 = (mt - gto) * BM;
    const u16* Wb = Wt2 + (size_t)g * (ID * HD);
    int n0 = bx * BN;
    int tid = threadIdx.x, lane = tid & 63, w = tid >> 6;
    int lm = lane >> 3;
    int lc = (((lane & 7) ^ lm) << 3);
    const u16* pa[4]; const u16* pb[2];
#pragma unroll
    for (int i = 0; i < 4; i++) {
        int gi = i * 8 + w;
        int r = row0 + gi * 8 + lm;
        r = (r < cnt) ? r : (cnt - 1);
        pa[i] = h1 + (size_t)(goff + r) * ID + lc;           // slot-indexed, perm'd
    }
#pragma unroll
    for (int i = 0; i < 2; i++) {
        int gi = i * 8 + w;
        pb[i] = Wb + (size_t)(n0 + gi * 8 + lm) * ID + lc;   // perm'd weights
    }
    int wr = w >> 1, wc = w & 1;
    int lr = lane & 15, l7 = lane & 7, q2 = lane >> 4;
    f32x4 acc[4][4] = {};

    auto stageA = [&](int b) {
        u16* A = S + b * 24576;
#pragma unroll
        for (int i = 0; i < 4; i++) { gl_lds16(pa[i], A + (i * 8 + w) * 512); pa[i] += BK; }
    };
    auto stageB = [&](int b) {
        u16* B = S + b * 24576 + 16384;
#pragma unroll
        for (int i = 0; i < 2; i++) { gl_lds16(pb[i], B + (i * 8 + w) * 512); pb[i] += BK; }
    };

    const int NK = ID / BK;                      // 22
    stageA(0); stageB(0); stageA(1); stageB(1);
    asm volatile("s_waitcnt vmcnt(6)" ::: "memory");
    __builtin_amdgcn_s_barrier();
    int cb = 0, sb = 2;
    for (int t = 0; t < NK; ++t) {
        const u16* A = S + cb * 24576;
        const u16* B = A + 16384;
        bool pf = (t + 2 < NK);
#pragma unroll
        for (int ph = 0; ph < 2; ++ph) {
            int slot = (((ph << 2) + q2) ^ l7) << 3;
            bf16x8 a[4], bb[4];
#pragma unroll
            for (int f = 0; f < 4; f++) {
                a[f]  = __builtin_bit_cast(bf16x8, *(const uint4*)&A[(wr * 64 + f * 16 + lr) * BK + slot]);
                bb[f] = __builtin_bit_cast(bf16x8, *(const uint4*)&B[(wc * 64 + f * 16 + lr) * BK + slot]);
            }
            if (pf) { if (ph == 0) stageA(sb); else stageB(sb); }
            __builtin_amdgcn_s_barrier();
            __builtin_amdgcn_s_setprio(1);
#pragma unroll
            for (int mf = 0; mf < 4; mf++)
#pragma unroll
                for (int nf = 0; nf < 4; nf++)
                    acc[mf][nf] = __builtin_amdgcn_mfma_f32_16x16x32_bf16(a[mf], bb[nf], acc[mf][nf], 0, 0, 0);
            __builtin_amdgcn_s_setprio(0);
            if (ph == 0) {
                __builtin_amdgcn_s_barrier();
            } else if (t + 1 < NK) {
                if (pf) asm volatile("s_waitcnt vmcnt(6)" ::: "memory");
                else    asm volatile("s_waitcnt vmcnt(0)" ::: "memory");
                __builtin_amdgcn_s_barrier();
            }
        }
        cb = (cb == 2) ? 0 : cb + 1;
        sb = (sb == 2) ? 0 : sb + 1;
    }

    int q4 = q2 * 4;
#pragma unroll
    for (int mf = 0; mf < 4; mf++)
#pragma unroll
        for (int reg = 0; reg < 4; reg++) {
            int r = row0 + wr * 64 + mf * 16 + q4 + reg;
            if (r < cnt) {
                int slot = goff + r;
                if (EO) {
                    size_t rb = (size_t)slot * HD + n0 + wc * 64;
#pragma unroll
                    for (int nf = 0; nf < 4; nf++)
                        eo[rb + nf * 16 + lr] = f2bf(acc[mf][nf][reg]);
                } else {
                    int tok = list[slot];
                    float wv = wgt[slot];
                    float* yr = y + (size_t)tok * HD + n0 + wc * 64;
#pragma unroll
                    for (int nf = 0; nf < 4; nf++)
                        atomicAdd(yr + nf * 16 + lr, acc[mf][nf][reg] * wv);
                }
            }
        }
}

// ---------------- combine: y[t] = w0*eo[s0] + w1*eo[s1] + eo[shared] --------
__global__ __launch_bounds__(256) void combine_kernel(
    const u16* __restrict__ eo, const int* __restrict__ smap,
    const float* __restrict__ tkv, const int* __restrict__ off,
    float* __restrict__ y) {
    int idx = blockIdx.x * 256 + threadIdx.x;
    int t = idx >> 8;
    int cc = (idx & 255) << 3;
    int s0 = smap[t * 2 + 0], s1 = smap[t * 2 + 1];
    float w0 = tkv[t * 2 + 0], w1 = tkv[t * 2 + 1];
    int s2 = off[NE] + t;
    uint4 A = *(const uint4*)(eo + (size_t)s0 * HD + cc);
    uint4 B = *(const uint4*)(eo + (size_t)s1 * HD + cc);
    uint4 C = *(const uint4*)(eo + (size_t)s2 * HD + cc);
    float4 o0, o1;
    o0.x = w0 * bflo(A.x) + w1 * bflo(B.x) + bflo(C.x);
    o0.y = w0 * bfhi(A.x) + w1 * bfhi(B.x) + bfhi(C.x);
    o0.z = w0 * bflo(A.y) + w1 * bflo(B.y) + bflo(C.y);
    o0.w = w0 * bfhi(A.y) + w1 * bfhi(B.y) + bfhi(C.y);
    o1.x = w0 * bflo(A.z) + w1 * bflo(B.z) + bflo(C.z);
    o1.y = w0 * bfhi(A.z) + w1 * bfhi(B.z) + bfhi(C.z);
    o1.z = w0 * bflo(A.w) + w1 * bflo(B.w) + bflo(C.w);
    o1.w = w0 * bfhi(A.w) + w1 * bfhi(B.w) + bfhi(C.w);
    float* yr = y + (size_t)t * HD + cc;
    *(float4*)yr = o0;
    *(float4*)(yr + 4) = o1;
}

// ---------------- launch -----------------------------------------------------
extern "C" void kernel_launch(void* const* d_in, const int* in_sizes, int n_in,
                              void* d_out, int out_size, void* d_ws, size_t ws_size,
                              hipStream_t stream) {
    const float* x   = (const float*)d_in[0];
    const float* gw  = (const float*)d_in[1];
    const float* W1  = (const float*)d_in[2];
    const float* W2  = (const float*)d_in[3];
    const float* Ws1 = (const float*)d_in[4];
    const float* Ws2 = (const float*)d_in[5];
    float* out = (float*)d_out;

    char* ws = (char*)d_ws;
    int*   counts  = (int*)(ws + 0);
    int*   cursor  = (int*)(ws + 64);
    int*   off     = (int*)(ws + 128);
    int*   tileoff = (int*)(ws + 192);
    float* imp     = (float*)(ws + 256);
    int*   tki     = (int*)(ws + 320);                    // becomes slot-map after scatter
    float* tkv     = (float*)(ws + 33088);
    int*   list    = (int*)(ws + 65856);
    float* wgt     = (float*)(ws + 115008);
    // big regions (bytes):
    //   xb  @ 164352        : 16,777,216
    //   Wt1 @ 16,941,568    : 51,904,512   (9 x 1408 x 2048 bf16)
    //   h1  @ 68,846,080    : 34,603,008   (12288 x 1408 bf16, perm'd cols)
    //   Wt2 @ 164352 (aliases xb+Wt1 after fc1) : 51,904,512
    //   eo  @ 103,449,088   : 50,331,648   (12288 x 2048 bf16) -- only if ws allows
    u16* xb  = (u16*)(ws + 164352);
    u16* wt1 = (u16*)(ws + 16941568ULL);
    u16* h1  = (u16*)(ws + 68846080ULL);
    u16* wt2 = (u16*)(ws + 164352);
    u16* eo  = (u16*)(ws + 103449088ULL);
    const bool use_eo = (ws_size >= 153780736ULL);

    if (!use_eo)
        hipMemsetAsync(d_out, 0, (size_t)out_size * sizeof(float), stream);
    hipMemsetAsync(d_ws, 0, 320, stream);

    router_kernel<<<NT / 4, 256, 0, stream>>>(x, gw, counts, imp, tki, tkv, xb);
    prep_kernel<<<1, 64, 0, stream>>>(counts, imp, off, tileoff, out + (size_t)NT * HD);
    scatter_kernel<<<NT / 256, 256, 0, stream>>>(tki, tkv, off, cursor, list, wgt);

    transw_kernel<<<dim3(ID / 64, HD / 64, NG), 256, 0, stream>>>(W1, Ws1, wt1, HD, ID);

    fc1_kernel<<<dim3(ID / BN, MT_MAX), 512, 0, stream>>>(xb, wt1, off, tileoff, list, h1);

    // Wt2 overwrites xb/Wt1 (both dead after fc1); stream order guarantees safety
    transw_kernel<<<dim3(HD / 64, ID / 64, NG), 256, 0, stream>>>(W2, Ws2, wt2, ID, HD);

    if (use_eo) {
        fc2_kernel<true><<<dim3(HD / BN, MT_MAX), 512, 0, stream>>>(
            h1, wt2, off, tileoff, list, wgt, eo, out);
        combine_kernel<<<NT, 256, 0, stream>>>(eo, tki, tkv, off, out);
    } else {
        fc2_kernel<false><<<dim3(HD / BN, MT_MAX), 512, 0, stream>>>(
            h1, wt2, off, tileoff, list, wgt, eo, out);
    }
}

// Round 10
// 311.072 us; speedup vs baseline: 1.8255x; 1.0977x over previous
//
#include <hip/hip_runtime.h>
#include <hip/hip_bf16.h>

#define NT 4096          // B*T tokens
#define HD 2048          // hidden
#define NE 8             // experts
#define TOPK 2
#define ID 1408          // intermediate
#define NG 9             // 8 experts + shared
#define BM 128
#define BN 64
#define BK 64
#define MT_MAX 104       // max sum of ceil(cnt/128) over groups (<=72) + 32 shared

typedef unsigned short u16;
typedef unsigned int u32;
typedef unsigned long long u64;
typedef __attribute__((ext_vector_type(8))) short bf16x8;
typedef __attribute__((ext_vector_type(4))) float f32x4;

__device__ __forceinline__ u16 f2bf(float f) {
    u32 u = __builtin_bit_cast(u32, f);
    u += 0x7FFFu + ((u >> 16) & 1u);   // round-to-nearest-even
    return (u16)(u >> 16);
}
__device__ __forceinline__ float bflo(u32 v) { return __builtin_bit_cast(float, v << 16); }
__device__ __forceinline__ float bfhi(u32 v) { return __builtin_bit_cast(float, v & 0xffff0000u); }

// async global->LDS, 16B per lane; lds base must be wave-uniform
typedef __attribute__((address_space(1))) const void gas_void;
typedef __attribute__((address_space(3))) void las_void;
__device__ __forceinline__ void gl_lds16(const void* g, void* l) {
    __builtin_amdgcn_global_load_lds((gas_void*)(u64)g, (las_void*)(u32)(u64)l, 16, 0, 0);
}

// ---------------- fused: router(+x->bf16 perm) blocks + transw(W1) blocks ---
// blocks [0, NT/4)            : router for 4 tokens each (fused convx)
// blocks [NT/4, NT/4 + 6336)  : transpose+convert W1/Ws1 -> wt1 (indep. work)
__global__ void router_tw1_kernel(const float* __restrict__ x, const float* __restrict__ gw,
                                  int* __restrict__ counts, float* __restrict__ imp,
                                  int* __restrict__ tki, float* __restrict__ tkv,
                                  u16* __restrict__ xb,
                                  const float* __restrict__ W1, const float* __restrict__ Ws1,
                                  u16* __restrict__ wt1) {
    __shared__ float s_imp[NE];
    __shared__ int s_cnt[NE];
    __shared__ u16 Lt[64][68];
    int tid = threadIdx.x;
    if (blockIdx.x < NT / 4) {
        // ---- router part ----
        if (tid < NE) { s_imp[tid] = 0.f; s_cnt[tid] = 0; }
        int w = tid >> 6, lane = tid & 63;
        int t = blockIdx.x * 4 + w;
        float acc[NE];
#pragma unroll
        for (int e = 0; e < NE; e++) acc[e] = 0.f;
        const float* xr = x + (size_t)t * HD;
        u16* xw = xb + (size_t)t * HD;
#pragma unroll
        for (int i = 0; i < 4; i++) {
            int cc = i * 64 + lane;
            int b64 = cc >> 3, j = cc & 7, h = j >> 2, q = j & 3;
            int k0 = b64 * 64 + h * 32 + q * 4;
            float4 v0 = *(const float4*)(xr + k0);
            float4 v1 = *(const float4*)(xr + k0 + 16);
#pragma unroll
            for (int e = 0; e < NE; e++) {
                const float* gp = gw + e * HD + k0;
                float4 g0 = *(const float4*)(gp);
                float4 g1 = *(const float4*)(gp + 16);
                acc[e] += v0.x * g0.x + v0.y * g0.y + v0.z * g0.z + v0.w * g0.w
                        + v1.x * g1.x + v1.y * g1.y + v1.z * g1.z + v1.w * g1.w;
            }
            ushort4 o0, o1;
            o0.x = f2bf(v0.x); o0.y = f2bf(v0.y); o0.z = f2bf(v0.z); o0.w = f2bf(v0.w);
            o1.x = f2bf(v1.x); o1.y = f2bf(v1.y); o1.z = f2bf(v1.z); o1.w = f2bf(v1.w);
            uint4 o;
            o.x = (u32)o0.x | ((u32)o0.y << 16); o.y = (u32)o0.z | ((u32)o0.w << 16);
            o.z = (u32)o1.x | ((u32)o1.y << 16); o.w = (u32)o1.z | ((u32)o1.w << 16);
            *(uint4*)(xw + b64 * 64 + j * 8) = o;
        }
#pragma unroll
        for (int e = 0; e < NE; e++) {
#pragma unroll
            for (int o = 32; o >= 1; o >>= 1) acc[e] += __shfl_xor(acc[e], o, 64);
        }
        __syncthreads();
        if (lane == 0) {
            float mx = acc[0];
            for (int e = 1; e < NE; e++) mx = fmaxf(mx, acc[e]);
            float p[NE], sum = 0.f;
            for (int e = 0; e < NE; e++) { p[e] = expf(acc[e] - mx); sum += p[e]; }
            float inv = 1.f / sum;
            for (int e = 0; e < NE; e++) p[e] *= inv;
            int i1 = 0;
            for (int e = 1; e < NE; e++) if (p[e] > p[i1]) i1 = e;
            int i2 = (i1 == 0) ? 1 : 0;
            for (int e = 0; e < NE; e++) if (e != i1 && p[e] > p[i2]) i2 = e;
            tki[t * 2 + 0] = i1; tkv[t * 2 + 0] = p[i1];
            tki[t * 2 + 1] = i2; tkv[t * 2 + 1] = p[i2];
            for (int e = 0; e < NE; e++) atomicAdd(&s_imp[e], p[e]);
            atomicAdd(&s_cnt[i1], 1); atomicAdd(&s_cnt[i2], 1);
        }
        __syncthreads();
        if (tid < NE) {
            atomicAdd(&imp[tid], s_imp[tid]);
            atomicAdd(&counts[tid], s_cnt[tid]);
        }
    } else {
        // ---- transw(W1) part: [K=HD][N=ID] f32 -> [N][K'] bf16, perm'd k ----
        int tw = blockIdx.x - NT / 4;
        int e = tw / 704, rem = tw % 704;       // 704 = (ID/64=22) * (HD/64=32)
        int n0 = (rem % 22) * 64, k0 = (rem / 22) * 64;
        const float* src = (e < NE) ? (W1 + (size_t)e * HD * ID) : Ws1;
        u16* dst = wt1 + (size_t)e * ID * HD;
#pragma unroll
        for (int i = 0; i < 4; i++) {
            int idx = i * 256 + tid;
            int kl = idx >> 4, nq = (idx & 15) * 4;
            float4 v = *(const float4*)(src + (size_t)(k0 + kl) * ID + n0 + nq);
            Lt[nq + 0][kl] = f2bf(v.x); Lt[nq + 1][kl] = f2bf(v.y);
            Lt[nq + 2][kl] = f2bf(v.z); Lt[nq + 3][kl] = f2bf(v.w);
        }
        __syncthreads();
#pragma unroll
        for (int c2 = 0; c2 < 2; c2++) {
            int cid = tid * 2 + c2;
            int nr = cid >> 3, j = cid & 7;
            int h = j >> 2, q = j & 3;
            int kb = h * 32 + q * 4;
            uint2 lo = *(const uint2*)&Lt[nr][kb];
            uint2 hi = *(const uint2*)&Lt[nr][kb + 16];
            uint4 o; o.x = lo.x; o.y = lo.y; o.z = hi.x; o.w = hi.y;
            *(uint4*)(dst + (size_t)(n0 + nr) * HD + k0 + j * 8) = o;
        }
    }
}

// ---------------- prep + scatter fused (single block, LDS cursors) ----------
__global__ void prepscat_kernel(const int* __restrict__ counts, const float* __restrict__ imp,
                                int* __restrict__ off, int* __restrict__ tileoff,
                                float* __restrict__ out_aux,
                                int* __restrict__ tki, const float* __restrict__ tkv,
                                int* __restrict__ list, float* __restrict__ wgt) {
    __shared__ int s_off[NG];
    __shared__ int s_cur[NE];
    int tid = threadIdx.x;
    if (tid == 0) {
        int o = 0, to = 0;
        for (int g = 0; g < NG; g++) {
            int c = (g < NE) ? counts[g] : NT;
            off[g] = o; s_off[g] = o; tileoff[g] = to;
            o += c; to += (c + BM - 1) / BM;
        }
        off[NG] = o; tileoff[NG] = to;
        float aux = 0.f;
        for (int e = 0; e < NE; e++)
            aux += (imp[e] / (float)NT) * ((float)counts[e] / (float)(NT * TOPK));
        *out_aux = aux * (float)NE;
    }
    if (tid < NE) s_cur[tid] = 0;
    __syncthreads();
    for (int t = tid; t < NT; t += 256) {
#pragma unroll
        for (int k = 0; k < TOPK; k++) {
            int e = tki[t * 2 + k];
            int pos = atomicAdd(&s_cur[e], 1);
            int s = s_off[e] + pos;
            list[s] = t;
            wgt[s] = tkv[t * 2 + k];
            tki[t * 2 + k] = s;                 // slot map
        }
        list[s_off[NE] + t] = t;
        wgt[s_off[NE] + t] = 1.0f;
    }
}

// ---------------- transpose+convert weights (W2 pass) -----------------------
__global__ void transw_kernel(const float* __restrict__ W, const float* __restrict__ Wsh,
                              u16* __restrict__ dst, int K, int N) {
    int e = blockIdx.z;
    const float* src = (e < NE) ? (W + (size_t)e * K * N) : Wsh;
    dst += (size_t)e * N * K;
    int k0 = blockIdx.y * 64, n0 = blockIdx.x * 64;
    __shared__ u16 Lt[64][68];
    int tid = threadIdx.x;
#pragma unroll
    for (int i = 0; i < 4; i++) {
        int idx = i * 256 + tid;
        int kl = idx >> 4, nq = (idx & 15) * 4;
        float4 v = *(const float4*)(src + (size_t)(k0 + kl) * N + n0 + nq);
        Lt[nq + 0][kl] = f2bf(v.x); Lt[nq + 1][kl] = f2bf(v.y);
        Lt[nq + 2][kl] = f2bf(v.z); Lt[nq + 3][kl] = f2bf(v.w);
    }
    __syncthreads();
#pragma unroll
    for (int c2 = 0; c2 < 2; c2++) {
        int cid = tid * 2 + c2;
        int nr = cid >> 3, j = cid & 7;
        int h = j >> 2, q = j & 3;
        int kb = h * 32 + q * 4;
        uint2 lo = *(const uint2*)&Lt[nr][kb];
        uint2 hi = *(const uint2*)&Lt[nr][kb + 16];
        uint4 o; o.x = lo.x; o.y = lo.y; o.z = hi.x; o.w = hi.y;
        *(uint4*)(dst + (size_t)(n0 + nr) * K + k0 + j * 8) = o;
    }
}

// ---------------- fc1 (round-6 config, measured best) -----------------------
// 128x64 tile, BK=64, 48KB LDS dbuf (3 blocks/CU), counted vmcnt(6),
// LDS XOR-swizzle via pre-swizzled global source.
__global__ __launch_bounds__(256) void fc1_kernel(
    const u16* __restrict__ xb, const u16* __restrict__ Wt1,
    const int* __restrict__ off, const int* __restrict__ tileoff,
    const int* __restrict__ list, u16* __restrict__ h1) {
    __shared__ u16 S[2 * 12288];   // per buffer: A 128x64 (16KB) + B 64x64 (8KB)
    int nwg = gridDim.x * gridDim.y;           // 22*104 = 2288, %8==0
    int orig = blockIdx.y * gridDim.x + blockIdx.x;
    int wg = (orig & 7) * (nwg >> 3) + (orig >> 3);
    int bx = wg % gridDim.x, mt = wg / gridDim.x;

    int g = -1, gto = 0;
#pragma unroll
    for (int gg = 0; gg < NG; gg++)
        if (mt >= tileoff[gg] && mt < tileoff[gg + 1]) { g = gg; gto = tileoff[gg]; }
    if (g < 0) return;
    int goff = off[g], cnt = off[g + 1] - goff;
    int row0 = (mt - gto) * BM;
    const u16* Wb = Wt1 + (size_t)g * (ID * HD);
    int n0 = bx * BN;
    int tid = threadIdx.x, lane = tid & 63, w = tid >> 6;
    int lm = lane >> 3;
    int lc = (((lane & 7) ^ lm) << 3);          // swizzled source chunk
    const u16* pa[4]; const u16* pb[2];
#pragma unroll
    for (int i = 0; i < 4; i++) {
        int c = i * 4 + w;
        int r = row0 + c * 8 + lm;
        r = (r < cnt) ? r : (cnt - 1);
        pa[i] = xb + (size_t)list[goff + r] * HD + lc;
    }
#pragma unroll
    for (int i = 0; i < 2; i++) {
        int c = i * 4 + w;
        pb[i] = Wb + (size_t)(n0 + c * 8 + lm) * HD + lc;
    }
    int wr = w >> 1, wc = w & 1;
    int lr = lane & 15, l7 = lane & 7, q2 = lane >> 4;
    f32x4 acc[4][2] = {};

    auto stage = [&](int b) {
        u16* A = S + b * 12288;
        u16* B = A + 8192;
#pragma unroll
        for (int i = 0; i < 4; i++) { gl_lds16(pa[i], A + (i * 4 + w) * 512); pa[i] += BK; }
#pragma unroll
        for (int i = 0; i < 2; i++) { gl_lds16(pb[i], B + (i * 4 + w) * 512); pb[i] += BK; }
    };
    auto compute = [&](int b) {
        const u16* A = S + b * 12288;
        const u16* B = A + 8192;
#pragma unroll
        for (int kc = 0; kc < 8; kc += 4) {
            int slot = ((kc + q2) ^ l7) << 3;
            bf16x8 a[4], bb[2];
#pragma unroll
            for (int f = 0; f < 4; f++)
                a[f] = __builtin_bit_cast(bf16x8, *(const uint4*)&A[(wr * 64 + f * 16 + lr) * BK + slot]);
#pragma unroll
            for (int f = 0; f < 2; f++)
                bb[f] = __builtin_bit_cast(bf16x8, *(const uint4*)&B[(wc * 32 + f * 16 + lr) * BK + slot]);
            __builtin_amdgcn_s_setprio(1);
#pragma unroll
            for (int mf = 0; mf < 4; mf++)
#pragma unroll
                for (int nf = 0; nf < 2; nf++)
                    acc[mf][nf] = __builtin_amdgcn_mfma_f32_16x16x32_bf16(a[mf], bb[nf], acc[mf][nf], 0, 0, 0);
            __builtin_amdgcn_s_setprio(0);
        }
    };

    stage(0);
    int cur = 0;
    for (int t = 1; t < HD / BK; ++t) {
        stage(cur ^ 1);
        asm volatile("s_waitcnt vmcnt(6)" ::: "memory");
        __builtin_amdgcn_s_barrier();
        compute(cur);
        asm volatile("s_waitcnt lgkmcnt(0)" ::: "memory");
        __builtin_amdgcn_s_barrier();
        cur ^= 1;
    }
    asm volatile("s_waitcnt vmcnt(0)" ::: "memory");
    __builtin_amdgcn_s_barrier();
    compute(cur);

    int q4 = q2 * 4;
    int cl = ((lr >> 2) << 3) + (lr & 3);
#pragma unroll
    for (int mf = 0; mf < 4; mf++)
#pragma unroll
        for (int reg = 0; reg < 4; reg++) {
            int r = row0 + wr * 64 + mf * 16 + q4 + reg;
            if (r < cnt) {
                size_t rb = (size_t)(goff + r) * ID + n0;
#pragma unroll
                for (int nf = 0; nf < 2; nf++) {
                    float v = acc[mf][nf][reg];
                    h1[rb + wc * 32 + (nf << 2) + cl] = f2bf(v / (1.f + __expf(-v)));
                }
            }
        }
}

// ---------------- fc2 (round-6 config): EO -> eo stores, else atomic y ------
template <bool EO>
__global__ __launch_bounds__(256) void fc2_kernel(
    const u16* __restrict__ h1, const u16* __restrict__ Wt2,
    const int* __restrict__ off, const int* __restrict__ tileoff,
    const int* __restrict__ list, const float* __restrict__ wgt,
    u16* __restrict__ eo, float* __restrict__ y) {
    __shared__ u16 S[2 * 12288];
    int nwg = gridDim.x * gridDim.y;            // 32*104 = 3328, %8==0
    int orig = blockIdx.y * gridDim.x + blockIdx.x;
    int wg = (orig & 7) * (nwg >> 3) + (orig >> 3);
    int bx = wg % gridDim.x, mt = wg / gridDim.x;

    int g = -1, gto = 0;
#pragma unroll
    for (int gg = 0; gg < NG; gg++)
        if (mt >= tileoff[gg] && mt < tileoff[gg + 1]) { g = gg; gto = tileoff[gg]; }
    if (g < 0) return;
    int goff = off[g], cnt = off[g + 1] - goff;
    int row0 = (mt - gto) * BM;
    const u16* Wb = Wt2 + (size_t)g * (ID * HD);
    int n0 = bx * BN;
    int tid = threadIdx.x, lane = tid & 63, w = tid >> 6;
    int lm = lane >> 3;
    int lc = (((lane & 7) ^ lm) << 3);
    const u16* pa[4]; const u16* pb[2];
#pragma unroll
    for (int i = 0; i < 4; i++) {
        int c = i * 4 + w;
        int r = row0 + c * 8 + lm;
        r = (r < cnt) ? r : (cnt - 1);
        pa[i] = h1 + (size_t)(goff + r) * ID + lc;           // slot-indexed, perm'd
    }
#pragma unroll
    for (int i = 0; i < 2; i++) {
        int c = i * 4 + w;
        pb[i] = Wb + (size_t)(n0 + c * 8 + lm) * ID + lc;    // perm'd weights
    }
    int wr = w >> 1, wc = w & 1;
    int lr = lane & 15, l7 = lane & 7, q2 = lane >> 4;
    f32x4 acc[4][2] = {};

    auto stage = [&](int b) {
        u16* A = S + b * 12288;
        u16* B = A + 8192;
#pragma unroll
        for (int i = 0; i < 4; i++) { gl_lds16(pa[i], A + (i * 4 + w) * 512); pa[i] += BK; }
#pragma unroll
        for (int i = 0; i < 2; i++) { gl_lds16(pb[i], B + (i * 4 + w) * 512); pb[i] += BK; }
    };
    auto compute = [&](int b) {
        const u16* A = S + b * 12288;
        const u16* B = A + 8192;
#pragma unroll
        for (int kc = 0; kc < 8; kc += 4) {
            int slot = ((kc + q2) ^ l7) << 3;
            bf16x8 a[4], bb[2];
#pragma unroll
            for (int f = 0; f < 4; f++)
                a[f] = __builtin_bit_cast(bf16x8, *(const uint4*)&A[(wr * 64 + f * 16 + lr) * BK + slot]);
#pragma unroll
            for (int f = 0; f < 2; f++)
                bb[f] = __builtin_bit_cast(bf16x8, *(const uint4*)&B[(wc * 32 + f * 16 + lr) * BK + slot]);
            __builtin_amdgcn_s_setprio(1);
#pragma unroll
            for (int mf = 0; mf < 4; mf++)
#pragma unroll
                for (int nf = 0; nf < 2; nf++)
                    acc[mf][nf] = __builtin_amdgcn_mfma_f32_16x16x32_bf16(a[mf], bb[nf], acc[mf][nf], 0, 0, 0);
            __builtin_amdgcn_s_setprio(0);
        }
    };

    stage(0);
    int cur = 0;
    for (int t = 1; t < ID / BK; ++t) {
        stage(cur ^ 1);
        asm volatile("s_waitcnt vmcnt(6)" ::: "memory");
        __builtin_amdgcn_s_barrier();
        compute(cur);
        asm volatile("s_waitcnt lgkmcnt(0)" ::: "memory");
        __builtin_amdgcn_s_barrier();
        cur ^= 1;
    }
    asm volatile("s_waitcnt vmcnt(0)" ::: "memory");
    __builtin_amdgcn_s_barrier();
    compute(cur);

    int q4 = q2 * 4;
#pragma unroll
    for (int mf = 0; mf < 4; mf++)
#pragma unroll
        for (int reg = 0; reg < 4; reg++) {
            int r = row0 + wr * 64 + mf * 16 + q4 + reg;
            if (r < cnt) {
                int slot = goff + r;
                if (EO) {
                    size_t rb = (size_t)slot * HD + n0 + wc * 32;
#pragma unroll
                    for (int nf = 0; nf < 2; nf++)
                        eo[rb + nf * 16 + lr] = f2bf(acc[mf][nf][reg]);
                } else {
                    int tok = list[slot];
                    float wv = wgt[slot];
                    float* yr = y + (size_t)tok * HD + n0 + wc * 32;
#pragma unroll
                    for (int nf = 0; nf < 2; nf++)
                        atomicAdd(yr + nf * 16 + lr, acc[mf][nf][reg] * wv);
                }
            }
        }
}

// ---------------- combine: y[t] = w0*eo[s0] + w1*eo[s1] + eo[shared] --------
__global__ __launch_bounds__(256) void combine_kernel(
    const u16* __restrict__ eo, const int* __restrict__ smap,
    const float* __restrict__ tkv, const int* __restrict__ off,
    float* __restrict__ y) {
    int idx = blockIdx.x * 256 + threadIdx.x;
    int t = idx >> 8;
    int cc = (idx & 255) << 3;
    int s0 = smap[t * 2 + 0], s1 = smap[t * 2 + 1];
    float w0 = tkv[t * 2 + 0], w1 = tkv[t * 2 + 1];
    int s2 = off[NE] + t;
    uint4 A = *(const uint4*)(eo + (size_t)s0 * HD + cc);
    uint4 B = *(const uint4*)(eo + (size_t)s1 * HD + cc);
    uint4 C = *(const uint4*)(eo + (size_t)s2 * HD + cc);
    float4 o0, o1;
    o0.x = w0 * bflo(A.x) + w1 * bflo(B.x) + bflo(C.x);
    o0.y = w0 * bfhi(A.x) + w1 * bfhi(B.x) + bfhi(C.x);
    o0.z = w0 * bflo(A.y) + w1 * bflo(B.y) + bflo(C.y);
    o0.w = w0 * bfhi(A.y) + w1 * bfhi(B.y) + bfhi(C.y);
    o1.x = w0 * bflo(A.z) + w1 * bflo(B.z) + bflo(C.z);
    o1.y = w0 * bfhi(A.z) + w1 * bfhi(B.z) + bfhi(C.z);
    o1.z = w0 * bflo(A.w) + w1 * bflo(B.w) + bflo(C.w);
    o1.w = w0 * bfhi(A.w) + w1 * bfhi(B.w) + bfhi(C.w);
    float* yr = y + (size_t)t * HD + cc;
    *(float4*)yr = o0;
    *(float4*)(yr + 4) = o1;
}

// ---------------- launch -----------------------------------------------------
extern "C" void kernel_launch(void* const* d_in, const int* in_sizes, int n_in,
                              void* d_out, int out_size, void* d_ws, size_t ws_size,
                              hipStream_t stream) {
    const float* x   = (const float*)d_in[0];
    const float* gw  = (const float*)d_in[1];
    const float* W1  = (const float*)d_in[2];
    const float* W2  = (const float*)d_in[3];
    const float* Ws1 = (const float*)d_in[4];
    const float* Ws2 = (const float*)d_in[5];
    float* out = (float*)d_out;

    char* ws = (char*)d_ws;
    int*   counts  = (int*)(ws + 0);
    int*   off     = (int*)(ws + 128);
    int*   tileoff = (int*)(ws + 192);
    float* imp     = (float*)(ws + 256);
    int*   tki     = (int*)(ws + 320);                    // becomes slot-map
    float* tkv     = (float*)(ws + 33088);
    int*   list    = (int*)(ws + 65856);
    float* wgt     = (float*)(ws + 115008);
    // big regions (bytes):
    //   xb  @ 164352        : 16,777,216
    //   Wt1 @ 16,941,568    : 51,904,512   (9 x 1408 x 2048 bf16)
    //   h1  @ 68,846,080    : 34,603,008   (12288 x 1408 bf16, perm'd cols)
    //   Wt2 @ 164352 (aliases xb+Wt1 after fc1) : 51,904,512
    //   eo  @ 103,449,088   : 50,331,648   (12288 x 2048 bf16) -- only if ws allows
    u16* xb  = (u16*)(ws + 164352);
    u16* wt1 = (u16*)(ws + 16941568ULL);
    u16* h1  = (u16*)(ws + 68846080ULL);
    u16* wt2 = (u16*)(ws + 164352);
    u16* eo  = (u16*)(ws + 103449088ULL);
    const bool use_eo = (ws_size >= 153780736ULL);

    if (!use_eo)
        hipMemsetAsync(d_out, 0, (size_t)out_size * sizeof(float), stream);
    hipMemsetAsync(d_ws, 0, 320, stream);

    // router (1024 blocks) || transw(W1) (6336 blocks) — independent work fused
    router_tw1_kernel<<<NT / 4 + 6336, 256, 0, stream>>>(
        x, gw, counts, imp, tki, tkv, xb, W1, Ws1, wt1);
    prepscat_kernel<<<1, 256, 0, stream>>>(
        counts, imp, off, tileoff, out + (size_t)NT * HD, tki, tkv, list, wgt);

    fc1_kernel<<<dim3(ID / BN, MT_MAX), 256, 0, stream>>>(xb, wt1, off, tileoff, list, h1);

    // Wt2 overwrites xb/Wt1 (both dead after fc1); stream order guarantees safety
    transw_kernel<<<dim3(HD / 64, ID / 64, NG), 256, 0, stream>>>(W2, Ws2, wt2, ID, HD);

    if (use_eo) {
        fc2_kernel<true><<<dim3(HD / BN, MT_MAX), 256, 0, stream>>>(
            h1, wt2, off, tileoff, list, wgt, eo, out);
        combine_kernel<<<NT, 256, 0, stream>>>(eo, tki, tkv, off, out);
    } else {
        fc2_kernel<false><<<dim3(HD / BN, MT_MAX), 256, 0, stream>>>(
            h1, wt2, off, tileoff, list, wgt, eo, out);
    }
}

// Round 11
// 305.431 us; speedup vs baseline: 1.8592x; 1.0185x over previous
//
#include <hip/hip_runtime.h>
#include <hip/hip_bf16.h>

#define NT 4096          // B*T tokens
#define HD 2048          // hidden
#define NE 8             // experts
#define TOPK 2
#define ID 1408          // intermediate
#define NG 9             // 8 experts + shared
#define BM 128
#define BN 64
#define BK 64
#define MT_MAX 104       // max sum of ceil(cnt/128) over groups (<=72) + 32 shared
#define NWG1 2288        // fc1 GEMM blocks = (ID/BN)=22 x MT_MAX=104
#define NTW 6336         // transpose blocks per weight set = 9 x 704

typedef unsigned short u16;
typedef unsigned int u32;
typedef unsigned long long u64;
typedef __attribute__((ext_vector_type(8))) short bf16x8;
typedef __attribute__((ext_vector_type(4))) float f32x4;

__device__ __forceinline__ u16 f2bf(float f) {
    u32 u = __builtin_bit_cast(u32, f);
    u += 0x7FFFu + ((u >> 16) & 1u);   // round-to-nearest-even
    return (u16)(u >> 16);
}
__device__ __forceinline__ float bflo(u32 v) { return __builtin_bit_cast(float, v << 16); }
__device__ __forceinline__ float bfhi(u32 v) { return __builtin_bit_cast(float, v & 0xffff0000u); }

// async global->LDS, 16B per lane; lds base must be wave-uniform
typedef __attribute__((address_space(1))) const void gas_void;
typedef __attribute__((address_space(3))) void las_void;
__device__ __forceinline__ void gl_lds16(const void* g, void* l) {
    __builtin_amdgcn_global_load_lds((gas_void*)(u64)g, (las_void*)(u32)(u64)l, 16, 0, 0);
}

// ---------------- fused: router(+x->bf16 perm) blocks + transw(W1) blocks ---
__global__ void router_tw1_kernel(const float* __restrict__ x, const float* __restrict__ gw,
                                  int* __restrict__ counts, float* __restrict__ imp,
                                  int* __restrict__ tki, float* __restrict__ tkv,
                                  u16* __restrict__ xb,
                                  const float* __restrict__ W1, const float* __restrict__ Ws1,
                                  u16* __restrict__ wt1) {
    __shared__ float s_imp[NE];
    __shared__ int s_cnt[NE];
    __shared__ u16 Lt[64][68];
    int tid = threadIdx.x;
    if (blockIdx.x < NT / 4) {
        // ---- router part ----
        if (tid < NE) { s_imp[tid] = 0.f; s_cnt[tid] = 0; }
        int w = tid >> 6, lane = tid & 63;
        int t = blockIdx.x * 4 + w;
        float acc[NE];
#pragma unroll
        for (int e = 0; e < NE; e++) acc[e] = 0.f;
        const float* xr = x + (size_t)t * HD;
        u16* xw = xb + (size_t)t * HD;
#pragma unroll
        for (int i = 0; i < 4; i++) {
            int cc = i * 64 + lane;
            int b64 = cc >> 3, j = cc & 7, h = j >> 2, q = j & 3;
            int k0 = b64 * 64 + h * 32 + q * 4;
            float4 v0 = *(const float4*)(xr + k0);
            float4 v1 = *(const float4*)(xr + k0 + 16);
#pragma unroll
            for (int e = 0; e < NE; e++) {
                const float* gp = gw + e * HD + k0;
                float4 g0 = *(const float4*)(gp);
                float4 g1 = *(const float4*)(gp + 16);
                acc[e] += v0.x * g0.x + v0.y * g0.y + v0.z * g0.z + v0.w * g0.w
                        + v1.x * g1.x + v1.y * g1.y + v1.z * g1.z + v1.w * g1.w;
            }
            ushort4 o0, o1;
            o0.x = f2bf(v0.x); o0.y = f2bf(v0.y); o0.z = f2bf(v0.z); o0.w = f2bf(v0.w);
            o1.x = f2bf(v1.x); o1.y = f2bf(v1.y); o1.z = f2bf(v1.z); o1.w = f2bf(v1.w);
            uint4 o;
            o.x = (u32)o0.x | ((u32)o0.y << 16); o.y = (u32)o0.z | ((u32)o0.w << 16);
            o.z = (u32)o1.x | ((u32)o1.y << 16); o.w = (u32)o1.z | ((u32)o1.w << 16);
            *(uint4*)(xw + b64 * 64 + j * 8) = o;
        }
#pragma unroll
        for (int e = 0; e < NE; e++) {
#pragma unroll
            for (int o = 32; o >= 1; o >>= 1) acc[e] += __shfl_xor(acc[e], o, 64);
        }
        __syncthreads();
        if (lane == 0) {
            float mx = acc[0];
            for (int e = 1; e < NE; e++) mx = fmaxf(mx, acc[e]);
            float p[NE], sum = 0.f;
            for (int e = 0; e < NE; e++) { p[e] = expf(acc[e] - mx); sum += p[e]; }
            float inv = 1.f / sum;
            for (int e = 0; e < NE; e++) p[e] *= inv;
            int i1 = 0;
            for (int e = 1; e < NE; e++) if (p[e] > p[i1]) i1 = e;
            int i2 = (i1 == 0) ? 1 : 0;
            for (int e = 0; e < NE; e++) if (e != i1 && p[e] > p[i2]) i2 = e;
            tki[t * 2 + 0] = i1; tkv[t * 2 + 0] = p[i1];
            tki[t * 2 + 1] = i2; tkv[t * 2 + 1] = p[i2];
            for (int e = 0; e < NE; e++) atomicAdd(&s_imp[e], p[e]);
            atomicAdd(&s_cnt[i1], 1); atomicAdd(&s_cnt[i2], 1);
        }
        __syncthreads();
        if (tid < NE) {
            atomicAdd(&imp[tid], s_imp[tid]);
            atomicAdd(&counts[tid], s_cnt[tid]);
        }
    } else {
        // ---- transw(W1) part: [K=HD][N=ID] f32 -> [N][K'] bf16, perm'd k ----
        int tw = blockIdx.x - NT / 4;
        int e = tw / 704, rem = tw % 704;       // 704 = (ID/64=22) * (HD/64=32)
        int n0 = (rem % 22) * 64, k0 = (rem / 22) * 64;
        const float* src = (e < NE) ? (W1 + (size_t)e * HD * ID) : Ws1;
        u16* dst = wt1 + (size_t)e * ID * HD;
#pragma unroll
        for (int i = 0; i < 4; i++) {
            int idx = i * 256 + tid;
            int kl = idx >> 4, nq = (idx & 15) * 4;
            float4 v = *(const float4*)(src + (size_t)(k0 + kl) * ID + n0 + nq);
            Lt[nq + 0][kl] = f2bf(v.x); Lt[nq + 1][kl] = f2bf(v.y);
            Lt[nq + 2][kl] = f2bf(v.z); Lt[nq + 3][kl] = f2bf(v.w);
        }
        __syncthreads();
#pragma unroll
        for (int c2 = 0; c2 < 2; c2++) {
            int cid = tid * 2 + c2;
            int nr = cid >> 3, j = cid & 7;
            int h = j >> 2, q = j & 3;
            int kb = h * 32 + q * 4;
            uint2 lo = *(const uint2*)&Lt[nr][kb];
            uint2 hi = *(const uint2*)&Lt[nr][kb + 16];
            uint4 o; o.x = lo.x; o.y = lo.y; o.z = hi.x; o.w = hi.y;
            *(uint4*)(dst + (size_t)(n0 + nr) * HD + k0 + j * 8) = o;
        }
    }
}

// ---------------- prep + scatter fused (single block, LDS cursors) ----------
__global__ void prepscat_kernel(const int* __restrict__ counts, const float* __restrict__ imp,
                                int* __restrict__ off, int* __restrict__ tileoff,
                                float* __restrict__ out_aux,
                                int* __restrict__ tki, const float* __restrict__ tkv,
                                int* __restrict__ list, float* __restrict__ wgt) {
    __shared__ int s_off[NG];
    __shared__ int s_cur[NE];
    int tid = threadIdx.x;
    if (tid == 0) {
        int o = 0, to = 0;
        for (int g = 0; g < NG; g++) {
            int c = (g < NE) ? counts[g] : NT;
            off[g] = o; s_off[g] = o; tileoff[g] = to;
            o += c; to += (c + BM - 1) / BM;
        }
        off[NG] = o; tileoff[NG] = to;
        float aux = 0.f;
        for (int e = 0; e < NE; e++)
            aux += (imp[e] / (float)NT) * ((float)counts[e] / (float)(NT * TOPK));
        *out_aux = aux * (float)NE;
    }
    if (tid < NE) s_cur[tid] = 0;
    __syncthreads();
    for (int t = tid; t < NT; t += 256) {
#pragma unroll
        for (int k = 0; k < TOPK; k++) {
            int e = tki[t * 2 + k];
            int pos = atomicAdd(&s_cur[e], 1);
            int s = s_off[e] + pos;
            list[s] = t;
            wgt[s] = tkv[t * 2 + k];
            tki[t * 2 + k] = s;                 // slot map
        }
        list[s_off[NE] + t] = t;
        wgt[s_off[NE] + t] = 1.0f;
    }
}

// ---------------- transpose+convert weights (fallback W2 pass) --------------
__global__ void transw_kernel(const float* __restrict__ W, const float* __restrict__ Wsh,
                              u16* __restrict__ dst, int K, int N) {
    int e = blockIdx.z;
    const float* src = (e < NE) ? (W + (size_t)e * K * N) : Wsh;
    dst += (size_t)e * N * K;
    int k0 = blockIdx.y * 64, n0 = blockIdx.x * 64;
    __shared__ u16 Lt[64][68];
    int tid = threadIdx.x;
#pragma unroll
    for (int i = 0; i < 4; i++) {
        int idx = i * 256 + tid;
        int kl = idx >> 4, nq = (idx & 15) * 4;
        float4 v = *(const float4*)(src + (size_t)(k0 + kl) * N + n0 + nq);
        Lt[nq + 0][kl] = f2bf(v.x); Lt[nq + 1][kl] = f2bf(v.y);
        Lt[nq + 2][kl] = f2bf(v.z); Lt[nq + 3][kl] = f2bf(v.w);
    }
    __syncthreads();
#pragma unroll
    for (int c2 = 0; c2 < 2; c2++) {
        int cid = tid * 2 + c2;
        int nr = cid >> 3, j = cid & 7;
        int h = j >> 2, q = j & 3;
        int kb = h * 32 + q * 4;
        uint2 lo = *(const uint2*)&Lt[nr][kb];
        uint2 hi = *(const uint2*)&Lt[nr][kb + 16];
        uint4 o; o.x = lo.x; o.y = lo.y; o.z = hi.x; o.w = hi.y;
        *(uint4*)(dst + (size_t)(n0 + nr) * K + k0 + j * 8) = o;
    }
}

// ---------------- fc1 (round-6 config) + optional fused transw(W2) ----------
// GEMM blocks [0, NWG1): 128x64 tile, BK=64, 48KB LDS dbuf (3 blocks/CU),
// counted vmcnt(6), LDS XOR-swizzle via pre-swizzled global source.
// If FTW: blocks [NWG1, NWG1+NTW) transpose W2/Ws2 -> wt2 (disjoint buffer),
// riding fc1's spare HBM bandwidth (fc1 uses ~1.7 of ~6 TB/s).
template <bool FTW>
__global__ __launch_bounds__(256) void fc1_kernel(
    const u16* __restrict__ xb, const u16* __restrict__ Wt1,
    const int* __restrict__ off, const int* __restrict__ tileoff,
    const int* __restrict__ list, u16* __restrict__ h1,
    const float* __restrict__ W2, const float* __restrict__ Ws2,
    u16* __restrict__ wt2) {
    __shared__ u16 S[2 * 12288];   // per buffer: A 128x64 (16KB) + B 64x64 (8KB)
    int wg0 = blockIdx.x;
    int tid = threadIdx.x;
    if (FTW && wg0 >= NWG1) {
        // ---- transw(W2): [K=ID][N=HD] f32 -> [N][K'] bf16, perm'd k --------
        u16 (*Lt)[68] = (u16(*)[68])S;
        int tw = wg0 - NWG1;
        int e = tw / 704, rem = tw % 704;       // 704 = (HD/64=32) * (ID/64=22)
        int n0 = (rem % 32) * 64, k0 = (rem / 32) * 64;
        const float* src = (e < NE) ? (W2 + (size_t)e * ID * HD) : Ws2;
        u16* dst = wt2 + (size_t)e * HD * ID;
#pragma unroll
        for (int i = 0; i < 4; i++) {
            int idx = i * 256 + tid;
            int kl = idx >> 4, nq = (idx & 15) * 4;
            float4 v = *(const float4*)(src + (size_t)(k0 + kl) * HD + n0 + nq);
            Lt[nq + 0][kl] = f2bf(v.x); Lt[nq + 1][kl] = f2bf(v.y);
            Lt[nq + 2][kl] = f2bf(v.z); Lt[nq + 3][kl] = f2bf(v.w);
        }
        __syncthreads();
#pragma unroll
        for (int c2 = 0; c2 < 2; c2++) {
            int cid = tid * 2 + c2;
            int nr = cid >> 3, j = cid & 7;
            int h = j >> 2, q = j & 3;
            int kb = h * 32 + q * 4;
            uint2 lo = *(const uint2*)&Lt[nr][kb];
            uint2 hi = *(const uint2*)&Lt[nr][kb + 16];
            uint4 o; o.x = lo.x; o.y = lo.y; o.z = hi.x; o.w = hi.y;
            *(uint4*)(dst + (size_t)(n0 + nr) * ID + k0 + j * 8) = o;
        }
        return;
    }
    // ---- GEMM part ----
    int orig = wg0;                              // < NWG1 = 2288, %8==0
    int wg = (orig & 7) * (NWG1 >> 3) + (orig >> 3);
    int bx = wg % (ID / BN), mt = wg / (ID / BN);

    int g = -1, gto = 0;
#pragma unroll
    for (int gg = 0; gg < NG; gg++)
        if (mt >= tileoff[gg] && mt < tileoff[gg + 1]) { g = gg; gto = tileoff[gg]; }
    if (g < 0) return;
    int goff = off[g], cnt = off[g + 1] - goff;
    int row0 = (mt - gto) * BM;
    const u16* Wb = Wt1 + (size_t)g * (ID * HD);
    int n0 = bx * BN;
    int lane = tid & 63, w = tid >> 6;
    int lm = lane >> 3;
    int lc = (((lane & 7) ^ lm) << 3);          // swizzled source chunk
    const u16* pa[4]; const u16* pb[2];
#pragma unroll
    for (int i = 0; i < 4; i++) {
        int c = i * 4 + w;
        int r = row0 + c * 8 + lm;
        r = (r < cnt) ? r : (cnt - 1);
        pa[i] = xb + (size_t)list[goff + r] * HD + lc;
    }
#pragma unroll
    for (int i = 0; i < 2; i++) {
        int c = i * 4 + w;
        pb[i] = Wb + (size_t)(n0 + c * 8 + lm) * HD + lc;
    }
    int wr = w >> 1, wc = w & 1;
    int lr = lane & 15, l7 = lane & 7, q2 = lane >> 4;
    f32x4 acc[4][2] = {};

    auto stage = [&](int b) {
        u16* A = S + b * 12288;
        u16* B = A + 8192;
#pragma unroll
        for (int i = 0; i < 4; i++) { gl_lds16(pa[i], A + (i * 4 + w) * 512); pa[i] += BK; }
#pragma unroll
        for (int i = 0; i < 2; i++) { gl_lds16(pb[i], B + (i * 4 + w) * 512); pb[i] += BK; }
    };
    auto compute = [&](int b) {
        const u16* A = S + b * 12288;
        const u16* B = A + 8192;
#pragma unroll
        for (int kc = 0; kc < 8; kc += 4) {
            int slot = ((kc + q2) ^ l7) << 3;
            bf16x8 a[4], bb[2];
#pragma unroll
            for (int f = 0; f < 4; f++)
                a[f] = __builtin_bit_cast(bf16x8, *(const uint4*)&A[(wr * 64 + f * 16 + lr) * BK + slot]);
#pragma unroll
            for (int f = 0; f < 2; f++)
                bb[f] = __builtin_bit_cast(bf16x8, *(const uint4*)&B[(wc * 32 + f * 16 + lr) * BK + slot]);
            __builtin_amdgcn_s_setprio(1);
#pragma unroll
            for (int mf = 0; mf < 4; mf++)
#pragma unroll
                for (int nf = 0; nf < 2; nf++)
                    acc[mf][nf] = __builtin_amdgcn_mfma_f32_16x16x32_bf16(a[mf], bb[nf], acc[mf][nf], 0, 0, 0);
            __builtin_amdgcn_s_setprio(0);
        }
    };

    stage(0);
    int cur = 0;
    for (int t = 1; t < HD / BK; ++t) {
        stage(cur ^ 1);
        asm volatile("s_waitcnt vmcnt(6)" ::: "memory");
        __builtin_amdgcn_s_barrier();
        compute(cur);
        asm volatile("s_waitcnt lgkmcnt(0)" ::: "memory");
        __builtin_amdgcn_s_barrier();
        cur ^= 1;
    }
    asm volatile("s_waitcnt vmcnt(0)" ::: "memory");
    __builtin_amdgcn_s_barrier();
    compute(cur);

    int q4 = q2 * 4;
    int cl = ((lr >> 2) << 3) + (lr & 3);
#pragma unroll
    for (int mf = 0; mf < 4; mf++)
#pragma unroll
        for (int reg = 0; reg < 4; reg++) {
            int r = row0 + wr * 64 + mf * 16 + q4 + reg;
            if (r < cnt) {
                size_t rb = (size_t)(goff + r) * ID + n0;
#pragma unroll
                for (int nf = 0; nf < 2; nf++) {
                    float v = acc[mf][nf][reg];
                    h1[rb + wc * 32 + (nf << 2) + cl] = f2bf(v / (1.f + __expf(-v)));
                }
            }
        }
}

// ---------------- fc2 (round-6 config): EO -> eo stores, else atomic y ------
template <bool EO>
__global__ __launch_bounds__(256) void fc2_kernel(
    const u16* __restrict__ h1, const u16* __restrict__ Wt2,
    const int* __restrict__ off, const int* __restrict__ tileoff,
    const int* __restrict__ list, const float* __restrict__ wgt,
    u16* __restrict__ eo, float* __restrict__ y) {
    __shared__ u16 S[2 * 12288];
    int nwg = gridDim.x * gridDim.y;            // 32*104 = 3328, %8==0
    int orig = blockIdx.y * gridDim.x + blockIdx.x;
    int wg = (orig & 7) * (nwg >> 3) + (orig >> 3);
    int bx = wg % gridDim.x, mt = wg / gridDim.x;

    int g = -1, gto = 0;
#pragma unroll
    for (int gg = 0; gg < NG; gg++)
        if (mt >= tileoff[gg] && mt < tileoff[gg + 1]) { g = gg; gto = tileoff[gg]; }
    if (g < 0) return;
    int goff = off[g], cnt = off[g + 1] - goff;
    int row0 = (mt - gto) * BM;
    const u16* Wb = Wt2 + (size_t)g * (ID * HD);
    int n0 = bx * BN;
    int tid = threadIdx.x, lane = tid & 63, w = tid >> 6;
    int lm = lane >> 3;
    int lc = (((lane & 7) ^ lm) << 3);
    const u16* pa[4]; const u16* pb[2];
#pragma unroll
    for (int i = 0; i < 4; i++) {
        int c = i * 4 + w;
        int r = row0 + c * 8 + lm;
        r = (r < cnt) ? r : (cnt - 1);
        pa[i] = h1 + (size_t)(goff + r) * ID + lc;           // slot-indexed, perm'd
    }
#pragma unroll
    for (int i = 0; i < 2; i++) {
        int c = i * 4 + w;
        pb[i] = Wb + (size_t)(n0 + c * 8 + lm) * ID + lc;    // perm'd weights
    }
    int wr = w >> 1, wc = w & 1;
    int lr = lane & 15, l7 = lane & 7, q2 = lane >> 4;
    f32x4 acc[4][2] = {};

    auto stage = [&](int b) {
        u16* A = S + b * 12288;
        u16* B = A + 8192;
#pragma unroll
        for (int i = 0; i < 4; i++) { gl_lds16(pa[i], A + (i * 4 + w) * 512); pa[i] += BK; }
#pragma unroll
        for (int i = 0; i < 2; i++) { gl_lds16(pb[i], B + (i * 4 + w) * 512); pb[i] += BK; }
    };
    auto compute = [&](int b) {
        const u16* A = S + b * 12288;
        const u16* B = A + 8192;
#pragma unroll
        for (int kc = 0; kc < 8; kc += 4) {
            int slot = ((kc + q2) ^ l7) << 3;
            bf16x8 a[4], bb[2];
#pragma unroll
            for (int f = 0; f < 4; f++)
                a[f] = __builtin_bit_cast(bf16x8, *(const uint4*)&A[(wr * 64 + f * 16 + lr) * BK + slot]);
#pragma unroll
            for (int f = 0; f < 2; f++)
                bb[f] = __builtin_bit_cast(bf16x8, *(const uint4*)&B[(wc * 32 + f * 16 + lr) * BK + slot]);
            __builtin_amdgcn_s_setprio(1);
#pragma unroll
            for (int mf = 0; mf < 4; mf++)
#pragma unroll
                for (int nf = 0; nf < 2; nf++)
                    acc[mf][nf] = __builtin_amdgcn_mfma_f32_16x16x32_bf16(a[mf], bb[nf], acc[mf][nf], 0, 0, 0);
            __builtin_amdgcn_s_setprio(0);
        }
    };

    stage(0);
    int cur = 0;
    for (int t = 1; t < ID / BK; ++t) {
        stage(cur ^ 1);
        asm volatile("s_waitcnt vmcnt(6)" ::: "memory");
        __builtin_amdgcn_s_barrier();
        compute(cur);
        asm volatile("s_waitcnt lgkmcnt(0)" ::: "memory");
        __builtin_amdgcn_s_barrier();
        cur ^= 1;
    }
    asm volatile("s_waitcnt vmcnt(0)" ::: "memory");
    __builtin_amdgcn_s_barrier();
    compute(cur);

    int q4 = q2 * 4;
#pragma unroll
    for (int mf = 0; mf < 4; mf++)
#pragma unroll
        for (int reg = 0; reg < 4; reg++) {
            int r = row0 + wr * 64 + mf * 16 + q4 + reg;
            if (r < cnt) {
                int slot = goff + r;
                if (EO) {
                    size_t rb = (size_t)slot * HD + n0 + wc * 32;
#pragma unroll
                    for (int nf = 0; nf < 2; nf++)
                        eo[rb + nf * 16 + lr] = f2bf(acc[mf][nf][reg]);
                } else {
                    int tok = list[slot];
                    float wv = wgt[slot];
                    float* yr = y + (size_t)tok * HD + n0 + wc * 32;
#pragma unroll
                    for (int nf = 0; nf < 2; nf++)
                        atomicAdd(yr + nf * 16 + lr, acc[mf][nf][reg] * wv);
                }
            }
        }
}

// ---------------- combine: y[t] = w0*eo[s0] + w1*eo[s1] + eo[shared] --------
__global__ __launch_bounds__(256) void combine_kernel(
    const u16* __restrict__ eo, const int* __restrict__ smap,
    const float* __restrict__ tkv, const int* __restrict__ off,
    float* __restrict__ y) {
    int idx = blockIdx.x * 256 + threadIdx.x;
    int t = idx >> 8;
    int cc = (idx & 255) << 3;
    int s0 = smap[t * 2 + 0], s1 = smap[t * 2 + 1];
    float w0 = tkv[t * 2 + 0], w1 = tkv[t * 2 + 1];
    int s2 = off[NE] + t;
    uint4 A = *(const uint4*)(eo + (size_t)s0 * HD + cc);
    uint4 B = *(const uint4*)(eo + (size_t)s1 * HD + cc);
    uint4 C = *(const uint4*)(eo + (size_t)s2 * HD + cc);
    float4 o0, o1;
    o0.x = w0 * bflo(A.x) + w1 * bflo(B.x) + bflo(C.x);
    o0.y = w0 * bfhi(A.x) + w1 * bfhi(B.x) + bfhi(C.x);
    o0.z = w0 * bflo(A.y) + w1 * bflo(B.y) + bflo(C.y);
    o0.w = w0 * bfhi(A.y) + w1 * bfhi(B.y) + bfhi(C.y);
    o1.x = w0 * bflo(A.z) + w1 * bflo(B.z) + bflo(C.z);
    o1.y = w0 * bfhi(A.z) + w1 * bfhi(B.z) + bfhi(C.z);
    o1.z = w0 * bflo(A.w) + w1 * bflo(B.w) + bflo(C.w);
    o1.w = w0 * bfhi(A.w) + w1 * bfhi(B.w) + bfhi(C.w);
    float* yr = y + (size_t)t * HD + cc;
    *(float4*)yr = o0;
    *(float4*)(yr + 4) = o1;
}

// ---------------- launch -----------------------------------------------------
extern "C" void kernel_launch(void* const* d_in, const int* in_sizes, int n_in,
                              void* d_out, int out_size, void* d_ws, size_t ws_size,
                              hipStream_t stream) {
    const float* x   = (const float*)d_in[0];
    const float* gw  = (const float*)d_in[1];
    const float* W1  = (const float*)d_in[2];
    const float* W2  = (const float*)d_in[3];
    const float* Ws1 = (const float*)d_in[4];
    const float* Ws2 = (const float*)d_in[5];
    float* out = (float*)d_out;

    char* ws = (char*)d_ws;
    int*   counts  = (int*)(ws + 0);
    int*   off     = (int*)(ws + 128);
    int*   tileoff = (int*)(ws + 192);
    float* imp     = (float*)(ws + 256);
    int*   tki     = (int*)(ws + 320);                    // becomes slot-map
    float* tkv     = (float*)(ws + 33088);
    int*   list    = (int*)(ws + 65856);
    float* wgt     = (float*)(ws + 115008);
    // big regions (bytes):
    //   xb  @ 164352        : 16,777,216
    //   Wt1 @ 16,941,568    : 51,904,512   (9 x 1408 x 2048 bf16)
    //   h1  @ 68,846,080    : 34,603,008   (12288 x 1408 bf16, perm'd cols)
    //   eo  @ 103,449,088   : 50,331,648   (12288 x 2048 bf16) -- if ws >= 153.8M
    //   Wt2: if ws >= 205,685,248 -> disjoint @153,780,736 (enables fc1-fusion)
    //        else aliases xb+Wt1 @164352 (serial transw2 after fc1)
    u16* xb  = (u16*)(ws + 164352);
    u16* wt1 = (u16*)(ws + 16941568ULL);
    u16* h1  = (u16*)(ws + 68846080ULL);
    u16* eo  = (u16*)(ws + 103449088ULL);
    const bool use_big = (ws_size >= 205685248ULL);
    const bool use_eo  = (ws_size >= 153780736ULL);
    u16* wt2 = use_big ? (u16*)(ws + 153780736ULL) : (u16*)(ws + 164352);

    if (!use_eo)
        hipMemsetAsync(d_out, 0, (size_t)out_size * sizeof(float), stream);
    hipMemsetAsync(d_ws, 0, 320, stream);

    // router (1024 blocks) || transw(W1) (6336 blocks) — independent work fused
    router_tw1_kernel<<<NT / 4 + NTW, 256, 0, stream>>>(
        x, gw, counts, imp, tki, tkv, xb, W1, Ws1, wt1);
    prepscat_kernel<<<1, 256, 0, stream>>>(
        counts, imp, off, tileoff, out + (size_t)NT * HD, tki, tkv, list, wgt);

    if (use_big) {
        // fc1 GEMM || transw(W2) fused — wt2 disjoint, rides fc1's spare BW
        fc1_kernel<true><<<NWG1 + NTW, 256, 0, stream>>>(
            xb, wt1, off, tileoff, list, h1, W2, Ws2, wt2);
    } else {
        fc1_kernel<false><<<NWG1, 256, 0, stream>>>(
            xb, wt1, off, tileoff, list, h1, W2, Ws2, wt2);
        // Wt2 overwrites xb/Wt1 (dead after fc1); stream order guarantees safety
        transw_kernel<<<dim3(HD / 64, ID / 64, NG), 256, 0, stream>>>(W2, Ws2, wt2, ID, HD);
    }

    if (use_eo) {
        fc2_kernel<true><<<dim3(HD / BN, MT_MAX), 256, 0, stream>>>(
            h1, wt2, off, tileoff, list, wgt, eo, out);
        combine_kernel<<<NT, 256, 0, stream>>>(eo, tki, tkv, off, out);
    } else {
        fc2_kernel<false><<<dim3(HD / BN, MT_MAX), 256, 0, stream>>>(
            h1, wt2, off, tileoff, list, wgt, eo, out);
    }
}

// Round 12
// 272.409 us; speedup vs baseline: 2.0846x; 1.1212x over previous
//
#include <hip/hip_runtime.h>
#include <hip/hip_bf16.h>

#define NT 4096          // B*T tokens
#define HD 2048          // hidden
#define NE 8             // experts
#define TOPK 2
#define ID 1408          // intermediate
#define NG 9             // 8 experts + shared
#define BM 128
#define BN 128
#define BK 64
#define MT_MAX 104       // max sum of ceil(cnt/128) over groups (<=72) + 32 shared
#define NWG1 1144        // fc1 GEMM blocks = (ID/BN)=11 x MT_MAX=104
#define NTW 6336         // transpose blocks per weight set = 9 x 704

typedef unsigned short u16;
typedef unsigned int u32;
typedef unsigned long long u64;
typedef __attribute__((ext_vector_type(8))) short bf16x8;
typedef __attribute__((ext_vector_type(4))) float f32x4;

__device__ __forceinline__ u16 f2bf(float f) {
    u32 u = __builtin_bit_cast(u32, f);
    u += 0x7FFFu + ((u >> 16) & 1u);   // round-to-nearest-even
    return (u16)(u >> 16);
}
__device__ __forceinline__ float bflo(u32 v) { return __builtin_bit_cast(float, v << 16); }
__device__ __forceinline__ float bfhi(u32 v) { return __builtin_bit_cast(float, v & 0xffff0000u); }

// async global->LDS, 16B per lane; lds base must be wave-uniform
typedef __attribute__((address_space(1))) const void gas_void;
typedef __attribute__((address_space(3))) void las_void;
__device__ __forceinline__ void gl_lds16(const void* g, void* l) {
    __builtin_amdgcn_global_load_lds((gas_void*)(u64)g, (las_void*)(u32)(u64)l, 16, 0, 0);
}

// ---------------- fused: router(+x->bf16 perm) blocks + transw(W1) blocks ---
__global__ void router_tw1_kernel(const float* __restrict__ x, const float* __restrict__ gw,
                                  int* __restrict__ counts, float* __restrict__ imp,
                                  int* __restrict__ tki, float* __restrict__ tkv,
                                  u16* __restrict__ xb,
                                  const float* __restrict__ W1, const float* __restrict__ Ws1,
                                  u16* __restrict__ wt1) {
    __shared__ float s_imp[NE];
    __shared__ int s_cnt[NE];
    __shared__ u16 Lt[64][68];
    int tid = threadIdx.x;
    if (blockIdx.x < NT / 4) {
        // ---- router part ----
        if (tid < NE) { s_imp[tid] = 0.f; s_cnt[tid] = 0; }
        int w = tid >> 6, lane = tid & 63;
        int t = blockIdx.x * 4 + w;
        float acc[NE];
#pragma unroll
        for (int e = 0; e < NE; e++) acc[e] = 0.f;
        const float* xr = x + (size_t)t * HD;
        u16* xw = xb + (size_t)t * HD;
#pragma unroll
        for (int i = 0; i < 4; i++) {
            int cc = i * 64 + lane;
            int b64 = cc >> 3, j = cc & 7, h = j >> 2, q = j & 3;
            int k0 = b64 * 64 + h * 32 + q * 4;
            float4 v0 = *(const float4*)(xr + k0);
            float4 v1 = *(const float4*)(xr + k0 + 16);
#pragma unroll
            for (int e = 0; e < NE; e++) {
                const float* gp = gw + e * HD + k0;
                float4 g0 = *(const float4*)(gp);
                float4 g1 = *(const float4*)(gp + 16);
                acc[e] += v0.x * g0.x + v0.y * g0.y + v0.z * g0.z + v0.w * g0.w
                        + v1.x * g1.x + v1.y * g1.y + v1.z * g1.z + v1.w * g1.w;
            }
            ushort4 o0, o1;
            o0.x = f2bf(v0.x); o0.y = f2bf(v0.y); o0.z = f2bf(v0.z); o0.w = f2bf(v0.w);
            o1.x = f2bf(v1.x); o1.y = f2bf(v1.y); o1.z = f2bf(v1.z); o1.w = f2bf(v1.w);
            uint4 o;
            o.x = (u32)o0.x | ((u32)o0.y << 16); o.y = (u32)o0.z | ((u32)o0.w << 16);
            o.z = (u32)o1.x | ((u32)o1.y << 16); o.w = (u32)o1.z | ((u32)o1.w << 16);
            *(uint4*)(xw + b64 * 64 + j * 8) = o;
        }
#pragma unroll
        for (int e = 0; e < NE; e++) {
#pragma unroll
            for (int o = 32; o >= 1; o >>= 1) acc[e] += __shfl_xor(acc[e], o, 64);
        }
        __syncthreads();
        if (lane == 0) {
            float mx = acc[0];
            for (int e = 1; e < NE; e++) mx = fmaxf(mx, acc[e]);
            float p[NE], sum = 0.f;
            for (int e = 0; e < NE; e++) { p[e] = expf(acc[e] - mx); sum += p[e]; }
            float inv = 1.f / sum;
            for (int e = 0; e < NE; e++) p[e] *= inv;
            int i1 = 0;
            for (int e = 1; e < NE; e++) if (p[e] > p[i1]) i1 = e;
            int i2 = (i1 == 0) ? 1 : 0;
            for (int e = 0; e < NE; e++) if (e != i1 && p[e] > p[i2]) i2 = e;
            tki[t * 2 + 0] = i1; tkv[t * 2 + 0] = p[i1];
            tki[t * 2 + 1] = i2; tkv[t * 2 + 1] = p[i2];
            for (int e = 0; e < NE; e++) atomicAdd(&s_imp[e], p[e]);
            atomicAdd(&s_cnt[i1], 1); atomicAdd(&s_cnt[i2], 1);
        }
        __syncthreads();
        if (tid < NE) {
            atomicAdd(&imp[tid], s_imp[tid]);
            atomicAdd(&counts[tid], s_cnt[tid]);
        }
    } else {
        // ---- transw(W1) part: [K=HD][N=ID] f32 -> [N][K'] bf16, perm'd k ----
        int tw = blockIdx.x - NT / 4;
        int e = tw / 704, rem = tw % 704;       // 704 = (ID/64=22) * (HD/64=32)
        int n0 = (rem % 22) * 64, k0 = (rem / 22) * 64;
        const float* src = (e < NE) ? (W1 + (size_t)e * HD * ID) : Ws1;
        u16* dst = wt1 + (size_t)e * ID * HD;
#pragma unroll
        for (int i = 0; i < 4; i++) {
            int idx = i * 256 + tid;
            int kl = idx >> 4, nq = (idx & 15) * 4;
            float4 v = *(const float4*)(src + (size_t)(k0 + kl) * ID + n0 + nq);
            Lt[nq + 0][kl] = f2bf(v.x); Lt[nq + 1][kl] = f2bf(v.y);
            Lt[nq + 2][kl] = f2bf(v.z); Lt[nq + 3][kl] = f2bf(v.w);
        }
        __syncthreads();
#pragma unroll
        for (int c2 = 0; c2 < 2; c2++) {
            int cid = tid * 2 + c2;
            int nr = cid >> 3, j = cid & 7;
            int h = j >> 2, q = j & 3;
            int kb = h * 32 + q * 4;
            uint2 lo = *(const uint2*)&Lt[nr][kb];
            uint2 hi = *(const uint2*)&Lt[nr][kb + 16];
            uint4 o; o.x = lo.x; o.y = lo.y; o.z = hi.x; o.w = hi.y;
            *(uint4*)(dst + (size_t)(n0 + nr) * HD + k0 + j * 8) = o;
        }
    }
}

// ---------------- prep + scatter fused (single block, LDS cursors) ----------
__global__ void prepscat_kernel(const int* __restrict__ counts, const float* __restrict__ imp,
                                int* __restrict__ off, int* __restrict__ tileoff,
                                float* __restrict__ out_aux,
                                int* __restrict__ tki, const float* __restrict__ tkv,
                                int* __restrict__ list, float* __restrict__ wgt) {
    __shared__ int s_off[NG];
    __shared__ int s_cur[NE];
    int tid = threadIdx.x;
    if (tid == 0) {
        int o = 0, to = 0;
        for (int g = 0; g < NG; g++) {
            int c = (g < NE) ? counts[g] : NT;
            off[g] = o; s_off[g] = o; tileoff[g] = to;
            o += c; to += (c + BM - 1) / BM;
        }
        off[NG] = o; tileoff[NG] = to;
        float aux = 0.f;
        for (int e = 0; e < NE; e++)
            aux += (imp[e] / (float)NT) * ((float)counts[e] / (float)(NT * TOPK));
        *out_aux = aux * (float)NE;
    }
    if (tid < NE) s_cur[tid] = 0;
    __syncthreads();
    for (int t = tid; t < NT; t += 256) {
#pragma unroll
        for (int k = 0; k < TOPK; k++) {
            int e = tki[t * 2 + k];
            int pos = atomicAdd(&s_cur[e], 1);
            int s = s_off[e] + pos;
            list[s] = t;
            wgt[s] = tkv[t * 2 + k];
            tki[t * 2 + k] = s;                 // slot map
        }
        list[s_off[NE] + t] = t;
        wgt[s_off[NE] + t] = 1.0f;
    }
}

// ---------------- transpose+convert weights (fallback W2 pass) --------------
__global__ void transw_kernel(const float* __restrict__ W, const float* __restrict__ Wsh,
                              u16* __restrict__ dst, int K, int N) {
    int e = blockIdx.z;
    const float* src = (e < NE) ? (W + (size_t)e * K * N) : Wsh;
    dst += (size_t)e * N * K;
    int k0 = blockIdx.y * 64, n0 = blockIdx.x * 64;
    __shared__ u16 Lt[64][68];
    int tid = threadIdx.x;
#pragma unroll
    for (int i = 0; i < 4; i++) {
        int idx = i * 256 + tid;
        int kl = idx >> 4, nq = (idx & 15) * 4;
        float4 v = *(const float4*)(src + (size_t)(k0 + kl) * N + n0 + nq);
        Lt[nq + 0][kl] = f2bf(v.x); Lt[nq + 1][kl] = f2bf(v.y);
        Lt[nq + 2][kl] = f2bf(v.z); Lt[nq + 3][kl] = f2bf(v.w);
    }
    __syncthreads();
#pragma unroll
    for (int c2 = 0; c2 < 2; c2++) {
        int cid = tid * 2 + c2;
        int nr = cid >> 3, j = cid & 7;
        int h = j >> 2, q = j & 3;
        int kb = h * 32 + q * 4;
        uint2 lo = *(const uint2*)&Lt[nr][kb];
        uint2 hi = *(const uint2*)&Lt[nr][kb + 16];
        uint4 o; o.x = lo.x; o.y = lo.y; o.z = hi.x; o.w = hi.y;
        *(uint4*)(dst + (size_t)(n0 + nr) * K + k0 + j * 8) = o;
    }
}

// ---------------- fc1: 128x128 tile, 512 thr (8 waves 2Mx4N), 64KB dbuf -----
// Per-wave work identical to round-6 (64x32 wave tile, 12 ds_read_b128 +
// 16 MFMA per K-step); 2 blocks/CU x 8 waves = 16 waves/CU (was 12).
// Stage = 4 gl_lds/thread -> counted vmcnt(4). XOR-swizzle unchanged.
// If FTW: blocks [NWG1, NWG1+NTW) transpose W2 -> wt2 (disjoint buffer).
template <bool FTW>
__global__ __launch_bounds__(512, 4) void fc1_kernel(
    const u16* __restrict__ xb, const u16* __restrict__ Wt1,
    const int* __restrict__ off, const int* __restrict__ tileoff,
    const int* __restrict__ list, u16* __restrict__ h1,
    const float* __restrict__ W2, const float* __restrict__ Ws2,
    u16* __restrict__ wt2) {
    __shared__ u16 S[2 * 16384];   // per buffer: A 128x64 (16KB) + B 128x64 (16KB)
    int wg0 = blockIdx.x;
    int tid = threadIdx.x;
    if (FTW && wg0 >= NWG1) {
        // ---- transw(W2): [K=ID][N=HD] f32 -> [N][K'] bf16, perm'd k --------
        u16 (*Lt)[68] = (u16(*)[68])S;
        int tw = wg0 - NWG1;
        int e = tw / 704, rem = tw % 704;       // 704 = (HD/64=32) * (ID/64=22)
        int n0 = (rem % 32) * 64, k0 = (rem / 32) * 64;
        const float* src = (e < NE) ? (W2 + (size_t)e * ID * HD) : Ws2;
        u16* dst = wt2 + (size_t)e * HD * ID;
#pragma unroll
        for (int i = 0; i < 2; i++) {
            int idx = i * 512 + tid;
            int kl = idx >> 4, nq = (idx & 15) * 4;
            float4 v = *(const float4*)(src + (size_t)(k0 + kl) * HD + n0 + nq);
            Lt[nq + 0][kl] = f2bf(v.x); Lt[nq + 1][kl] = f2bf(v.y);
            Lt[nq + 2][kl] = f2bf(v.z); Lt[nq + 3][kl] = f2bf(v.w);
        }
        __syncthreads();
        {
            int cid = tid;                       // 512 chunks = 64 rows x 8
            int nr = cid >> 3, j = cid & 7;
            int h = j >> 2, q = j & 3;
            int kb = h * 32 + q * 4;
            uint2 lo = *(const uint2*)&Lt[nr][kb];
            uint2 hi = *(const uint2*)&Lt[nr][kb + 16];
            uint4 o; o.x = lo.x; o.y = lo.y; o.z = hi.x; o.w = hi.y;
            *(uint4*)(dst + (size_t)(n0 + nr) * ID + k0 + j * 8) = o;
        }
        return;
    }
    // ---- GEMM part ----
    int wg = (wg0 & 7) * (NWG1 >> 3) + (wg0 >> 3);   // XCD swizzle, 1144 %8==0
    int bx = wg % (ID / BN), mt = wg / (ID / BN);

    int g = -1, gto = 0;
#pragma unroll
    for (int gg = 0; gg < NG; gg++)
        if (mt >= tileoff[gg] && mt < tileoff[gg + 1]) { g = gg; gto = tileoff[gg]; }
    if (g < 0) return;
    int goff = off[g], cnt = off[g + 1] - goff;
    int row0 = (mt - gto) * BM;
    const u16* Wb = Wt1 + (size_t)g * (ID * HD);
    int n0 = bx * BN;
    int lane = tid & 63, w = tid >> 6;
    int r0 = tid >> 3, r1 = 64 + r0;             // staging rows (2 loads/operand)
    int lc = (((tid & 7) ^ (r0 & 7)) << 3);      // swizzled source chunk
    int ra0 = row0 + r0; ra0 = (ra0 < cnt) ? ra0 : (cnt - 1);
    int ra1 = row0 + r1; ra1 = (ra1 < cnt) ? ra1 : (cnt - 1);
    const u16* pa0 = xb + (size_t)list[goff + ra0] * HD + lc;
    const u16* pa1 = xb + (size_t)list[goff + ra1] * HD + lc;
    const u16* pb0 = Wb + (size_t)(n0 + r0) * HD + lc;
    const u16* pb1 = Wb + (size_t)(n0 + r1) * HD + lc;

    int wr = w >> 2, wc = w & 3;
    int lr = lane & 15, l7 = lane & 7, q2 = lane >> 4;
    f32x4 acc[4][2] = {};

    auto stage = [&](int b) {
        u16* A = S + b * 16384;
        u16* B = A + 8192;
        gl_lds16(pa0, A + tid * 8);        pa0 += BK;
        gl_lds16(pa1, A + 4096 + tid * 8); pa1 += BK;
        gl_lds16(pb0, B + tid * 8);        pb0 += BK;
        gl_lds16(pb1, B + 4096 + tid * 8); pb1 += BK;
    };
    auto compute = [&](int b) {
        const u16* A = S + b * 16384;
        const u16* B = A + 8192;
#pragma unroll
        for (int kc = 0; kc < 8; kc += 4) {
            int slot = ((kc + q2) ^ l7) << 3;
            bf16x8 a[4], bb[2];
#pragma unroll
            for (int f = 0; f < 4; f++)
                a[f] = __builtin_bit_cast(bf16x8, *(const uint4*)&A[(wr * 64 + f * 16 + lr) * BK + slot]);
#pragma unroll
            for (int f = 0; f < 2; f++)
                bb[f] = __builtin_bit_cast(bf16x8, *(const uint4*)&B[(wc * 32 + f * 16 + lr) * BK + slot]);
            __builtin_amdgcn_s_setprio(1);
#pragma unroll
            for (int mf = 0; mf < 4; mf++)
#pragma unroll
                for (int nf = 0; nf < 2; nf++)
                    acc[mf][nf] = __builtin_amdgcn_mfma_f32_16x16x32_bf16(a[mf], bb[nf], acc[mf][nf], 0, 0, 0);
            __builtin_amdgcn_s_setprio(0);
        }
    };

    stage(0);
    int cur = 0;
    for (int t = 1; t < HD / BK; ++t) {
        stage(cur ^ 1);
        asm volatile("s_waitcnt vmcnt(4)" ::: "memory");
        __builtin_amdgcn_s_barrier();
        compute(cur);
        asm volatile("s_waitcnt lgkmcnt(0)" ::: "memory");
        __builtin_amdgcn_s_barrier();
        cur ^= 1;
    }
    asm volatile("s_waitcnt vmcnt(0)" ::: "memory");
    __builtin_amdgcn_s_barrier();
    compute(cur);

    int q4 = q2 * 4;
    int cl = ((lr >> 2) << 3) + (lr & 3);
#pragma unroll
    for (int mf = 0; mf < 4; mf++)
#pragma unroll
        for (int reg = 0; reg < 4; reg++) {
            int r = row0 + wr * 64 + mf * 16 + q4 + reg;
            if (r < cnt) {
                size_t rb = (size_t)(goff + r) * ID + n0;
#pragma unroll
                for (int nf = 0; nf < 2; nf++) {
                    float v = acc[mf][nf][reg];
                    h1[rb + wc * 32 + (nf << 2) + cl] = f2bf(v / (1.f + __expf(-v)));
                }
            }
        }
}

// ---------------- fc2: same geometry; EO -> eo stores, else atomic y --------
template <bool EO>
__global__ __launch_bounds__(512, 4) void fc2_kernel(
    const u16* __restrict__ h1, const u16* __restrict__ Wt2,
    const int* __restrict__ off, const int* __restrict__ tileoff,
    const int* __restrict__ list, const float* __restrict__ wgt,
    u16* __restrict__ eo, float* __restrict__ y) {
    __shared__ u16 S[2 * 16384];
    int nwg = gridDim.x * gridDim.y;            // 16*104 = 1664, %8==0
    int orig = blockIdx.y * gridDim.x + blockIdx.x;
    int wg = (orig & 7) * (nwg >> 3) + (orig >> 3);
    int bx = wg % gridDim.x, mt = wg / gridDim.x;

    int g = -1, gto = 0;
#pragma unroll
    for (int gg = 0; gg < NG; gg++)
        if (mt >= tileoff[gg] && mt < tileoff[gg + 1]) { g = gg; gto = tileoff[gg]; }
    if (g < 0) return;
    int goff = off[g], cnt = off[g + 1] - goff;
    int row0 = (mt - gto) * BM;
    const u16* Wb = Wt2 + (size_t)g * (ID * HD);
    int n0 = bx * BN;
    int tid = threadIdx.x, lane = tid & 63, w = tid >> 6;
    int r0 = tid >> 3, r1 = 64 + r0;
    int lc = (((tid & 7) ^ (r0 & 7)) << 3);
    int ra0 = row0 + r0; ra0 = (ra0 < cnt) ? ra0 : (cnt - 1);
    int ra1 = row0 + r1; ra1 = (ra1 < cnt) ? ra1 : (cnt - 1);
    const u16* pa0 = h1 + (size_t)(goff + ra0) * ID + lc;    // slot-indexed, perm'd
    const u16* pa1 = h1 + (size_t)(goff + ra1) * ID + lc;
    const u16* pb0 = Wb + (size_t)(n0 + r0) * ID + lc;       // perm'd weights
    const u16* pb1 = Wb + (size_t)(n0 + r1) * ID + lc;

    int wr = w >> 2, wc = w & 3;
    int lr = lane & 15, l7 = lane & 7, q2 = lane >> 4;
    f32x4 acc[4][2] = {};

    auto stage = [&](int b) {
        u16* A = S + b * 16384;
        u16* B = A + 8192;
        gl_lds16(pa0, A + tid * 8);        pa0 += BK;
        gl_lds16(pa1, A + 4096 + tid * 8); pa1 += BK;
        gl_lds16(pb0, B + tid * 8);        pb0 += BK;
        gl_lds16(pb1, B + 4096 + tid * 8); pb1 += BK;
    };
    auto compute = [&](int b) {
        const u16* A = S + b * 16384;
        const u16* B = A + 8192;
#pragma unroll
        for (int kc = 0; kc < 8; kc += 4) {
            int slot = ((kc + q2) ^ l7) << 3;
            bf16x8 a[4], bb[2];
#pragma unroll
            for (int f = 0; f < 4; f++)
                a[f] = __builtin_bit_cast(bf16x8, *(const uint4*)&A[(wr * 64 + f * 16 + lr) * BK + slot]);
#pragma unroll
            for (int f = 0; f < 2; f++)
                bb[f] = __builtin_bit_cast(bf16x8, *(const uint4*)&B[(wc * 32 + f * 16 + lr) * BK + slot]);
            __builtin_amdgcn_s_setprio(1);
#pragma unroll
            for (int mf = 0; mf < 4; mf++)
#pragma unroll
                for (int nf = 0; nf < 2; nf++)
                    acc[mf][nf] = __builtin_amdgcn_mfma_f32_16x16x32_bf16(a[mf], bb[nf], acc[mf][nf], 0, 0, 0);
            __builtin_amdgcn_s_setprio(0);
        }
    };

    stage(0);
    int cur = 0;
    for (int t = 1; t < ID / BK; ++t) {
        stage(cur ^ 1);
        asm volatile("s_waitcnt vmcnt(4)" ::: "memory");
        __builtin_amdgcn_s_barrier();
        compute(cur);
        asm volatile("s_waitcnt lgkmcnt(0)" ::: "memory");
        __builtin_amdgcn_s_barrier();
        cur ^= 1;
    }
    asm volatile("s_waitcnt vmcnt(0)" ::: "memory");
    __builtin_amdgcn_s_barrier();
    compute(cur);

    int q4 = q2 * 4;
#pragma unroll
    for (int mf = 0; mf < 4; mf++)
#pragma unroll
        for (int reg = 0; reg < 4; reg++) {
            int r = row0 + wr * 64 + mf * 16 + q4 + reg;
            if (r < cnt) {
                int slot = goff + r;
                if (EO) {
                    size_t rb = (size_t)slot * HD + n0 + wc * 32;
#pragma unroll
                    for (int nf = 0; nf < 2; nf++)
                        eo[rb + nf * 16 + lr] = f2bf(acc[mf][nf][reg]);
                } else {
                    int tok = list[slot];
                    float wv = wgt[slot];
                    float* yr = y + (size_t)tok * HD + n0 + wc * 32;
#pragma unroll
                    for (int nf = 0; nf < 2; nf++)
                        atomicAdd(yr + nf * 16 + lr, acc[mf][nf][reg] * wv);
                }
            }
        }
}

// ---------------- combine: y[t] = w0*eo[s0] + w1*eo[s1] + eo[shared] --------
__global__ __launch_bounds__(256) void combine_kernel(
    const u16* __restrict__ eo, const int* __restrict__ smap,
    const float* __restrict__ tkv, const int* __restrict__ off,
    float* __restrict__ y) {
    int idx = blockIdx.x * 256 + threadIdx.x;
    int t = idx >> 8;
    int cc = (idx & 255) << 3;
    int s0 = smap[t * 2 + 0], s1 = smap[t * 2 + 1];
    float w0 = tkv[t * 2 + 0], w1 = tkv[t * 2 + 1];
    int s2 = off[NE] + t;
    uint4 A = *(const uint4*)(eo + (size_t)s0 * HD + cc);
    uint4 B = *(const uint4*)(eo + (size_t)s1 * HD + cc);
    uint4 C = *(const uint4*)(eo + (size_t)s2 * HD + cc);
    float4 o0, o1;
    o0.x = w0 * bflo(A.x) + w1 * bflo(B.x) + bflo(C.x);
    o0.y = w0 * bfhi(A.x) + w1 * bfhi(B.x) + bfhi(C.x);
    o0.z = w0 * bflo(A.y) + w1 * bflo(B.y) + bflo(C.y);
    o0.w = w0 * bfhi(A.y) + w1 * bfhi(B.y) + bfhi(C.y);
    o1.x = w0 * bflo(A.z) + w1 * bflo(B.z) + bflo(C.z);
    o1.y = w0 * bfhi(A.z) + w1 * bfhi(B.z) + bfhi(C.z);
    o1.z = w0 * bflo(A.w) + w1 * bflo(B.w) + bflo(C.w);
    o1.w = w0 * bfhi(A.w) + w1 * bfhi(B.w) + bfhi(C.w);
    float* yr = y + (size_t)t * HD + cc;
    *(float4*)yr = o0;
    *(float4*)(yr + 4) = o1;
}

// ---------------- launch -----------------------------------------------------
extern "C" void kernel_launch(void* const* d_in, const int* in_sizes, int n_in,
                              void* d_out, int out_size, void* d_ws, size_t ws_size,
                              hipStream_t stream) {
    const float* x   = (const float*)d_in[0];
    const float* gw  = (const float*)d_in[1];
    const float* W1  = (const float*)d_in[2];
    const float* W2  = (const float*)d_in[3];
    const float* Ws1 = (const float*)d_in[4];
    const float* Ws2 = (const float*)d_in[5];
    float* out = (float*)d_out;

    char* ws = (char*)d_ws;
    int*   counts  = (int*)(ws + 0);
    int*   off     = (int*)(ws + 128);
    int*   tileoff = (int*)(ws + 192);
    float* imp     = (float*)(ws + 256);
    int*   tki     = (int*)(ws + 320);                    // becomes slot-map
    float* tkv     = (float*)(ws + 33088);
    int*   list    = (int*)(ws + 65856);
    float* wgt     = (float*)(ws + 115008);
    // big regions (bytes):
    //   xb  @ 164352        : 16,777,216
    //   Wt1 @ 16,941,568    : 51,904,512   (9 x 1408 x 2048 bf16)
    //   h1  @ 68,846,080    : 34,603,008   (12288 x 1408 bf16, perm'd cols)
    //   eo  @ 103,449,088   : 50,331,648   (12288 x 2048 bf16) -- if ws >= 153.8M
    //   Wt2: if ws >= 205,685,248 -> disjoint @153,780,736 (enables fc1-fusion)
    //        else aliases xb+Wt1 @164352 (serial transw2 after fc1)
    u16* xb  = (u16*)(ws + 164352);
    u16* wt1 = (u16*)(ws + 16941568ULL);
    u16* h1  = (u16*)(ws + 68846080ULL);
    u16* eo  = (u16*)(ws + 103449088ULL);
    const bool use_big = (ws_size >= 205685248ULL);
    const bool use_eo  = (ws_size >= 153780736ULL);
    u16* wt2 = use_big ? (u16*)(ws + 153780736ULL) : (u16*)(ws + 164352);

    if (!use_eo)
        hipMemsetAsync(d_out, 0, (size_t)out_size * sizeof(float), stream);
    hipMemsetAsync(d_ws, 0, 320, stream);

    // router (1024 blocks) || transw(W1) (6336 blocks) — independent work fused
    router_tw1_kernel<<<NT / 4 + NTW, 256, 0, stream>>>(
        x, gw, counts, imp, tki, tkv, xb, W1, Ws1, wt1);
    prepscat_kernel<<<1, 256, 0, stream>>>(
        counts, imp, off, tileoff, out + (size_t)NT * HD, tki, tkv, list, wgt);

    if (use_big) {
        // fc1 GEMM || transw(W2) fused — wt2 disjoint, rides fc1's spare BW
        fc1_kernel<true><<<NWG1 + NTW, 512, 0, stream>>>(
            xb, wt1, off, tileoff, list, h1, W2, Ws2, wt2);
    } else {
        fc1_kernel<false><<<NWG1, 512, 0, stream>>>(
            xb, wt1, off, tileoff, list, h1, W2, Ws2, wt2);
        // Wt2 overwrites xb/Wt1 (dead after fc1); stream order guarantees safety
        transw_kernel<<<dim3(HD / 64, ID / 64, NG), 256, 0, stream>>>(W2, Ws2, wt2, ID, HD);
    }

    if (use_eo) {
        fc2_kernel<true><<<dim3(HD / BN, MT_MAX), 512, 0, stream>>>(
            h1, wt2, off, tileoff, list, wgt, eo, out);
        combine_kernel<<<NT, 256, 0, stream>>>(eo, tki, tkv, off, out);
    } else {
        fc2_kernel<false><<<dim3(HD / BN, MT_MAX), 512, 0, stream>>>(
            h1, wt2, off, tileoff, list, wgt, eo, out);
    }
}

// Round 13
// 269.746 us; speedup vs baseline: 2.1051x; 1.0099x over previous
//
#include <hip/hip_runtime.h>
#include <hip/hip_bf16.h>

#define NT 4096          // B*T tokens
#define HD 2048          // hidden
#define NE 8             // experts
#define TOPK 2
#define ID 1408          // intermediate
#define NG 9             // 8 experts + shared
#define BM 192
#define BN 128
#define BK 64
#define MT_MAX 72        // Σceil(cnt/192) <= 50 experts + 22 shared
#define NWG1 792         // fc1 GEMM blocks = (ID/BN)=11 x 72   (%8==0)
#define NWG2 1152        // fc2 GEMM blocks = (HD/BN)=16 x 72   (%8==0)
#define NTW 6336         // transpose blocks per weight set = 9 x 704

typedef unsigned short u16;
typedef unsigned int u32;
typedef unsigned long long u64;
typedef __attribute__((ext_vector_type(8))) short bf16x8;
typedef __attribute__((ext_vector_type(4))) float f32x4;

__device__ __forceinline__ u16 f2bf(float f) {
    u32 u = __builtin_bit_cast(u32, f);
    u += 0x7FFFu + ((u >> 16) & 1u);   // round-to-nearest-even
    return (u16)(u >> 16);
}
__device__ __forceinline__ float bflo(u32 v) { return __builtin_bit_cast(float, v << 16); }
__device__ __forceinline__ float bfhi(u32 v) { return __builtin_bit_cast(float, v & 0xffff0000u); }

// async global->LDS, 16B per lane; lds base must be wave-uniform
typedef __attribute__((address_space(1))) const void gas_void;
typedef __attribute__((address_space(3))) void las_void;
__device__ __forceinline__ void gl_lds16(const void* g, void* l) {
    __builtin_amdgcn_global_load_lds((gas_void*)(u64)g, (las_void*)(u32)(u64)l, 16, 0, 0);
}

// ---------------- fused: router(+x->bf16 perm) blocks + transw(W1) blocks ---
__global__ void router_tw1_kernel(const float* __restrict__ x, const float* __restrict__ gw,
                                  int* __restrict__ counts, float* __restrict__ imp,
                                  int* __restrict__ tki, float* __restrict__ tkv,
                                  u16* __restrict__ xb,
                                  const float* __restrict__ W1, const float* __restrict__ Ws1,
                                  u16* __restrict__ wt1) {
    __shared__ float s_imp[NE];
    __shared__ int s_cnt[NE];
    __shared__ u16 Lt[64][68];
    int tid = threadIdx.x;
    if (blockIdx.x < NT / 4) {
        // ---- router part ----
        if (tid < NE) { s_imp[tid] = 0.f; s_cnt[tid] = 0; }
        int w = tid >> 6, lane = tid & 63;
        int t = blockIdx.x * 4 + w;
        float acc[NE];
#pragma unroll
        for (int e = 0; e < NE; e++) acc[e] = 0.f;
        const float* xr = x + (size_t)t * HD;
        u16* xw = xb + (size_t)t * HD;
#pragma unroll
        for (int i = 0; i < 4; i++) {
            int cc = i * 64 + lane;
            int b64 = cc >> 3, j = cc & 7, h = j >> 2, q = j & 3;
            int k0 = b64 * 64 + h * 32 + q * 4;
            float4 v0 = *(const float4*)(xr + k0);
            float4 v1 = *(const float4*)(xr + k0 + 16);
#pragma unroll
            for (int e = 0; e < NE; e++) {
                const float* gp = gw + e * HD + k0;
                float4 g0 = *(const float4*)(gp);
                float4 g1 = *(const float4*)(gp + 16);
                acc[e] += v0.x * g0.x + v0.y * g0.y + v0.z * g0.z + v0.w * g0.w
                        + v1.x * g1.x + v1.y * g1.y + v1.z * g1.z + v1.w * g1.w;
            }
            ushort4 o0, o1;
            o0.x = f2bf(v0.x); o0.y = f2bf(v0.y); o0.z = f2bf(v0.z); o0.w = f2bf(v0.w);
            o1.x = f2bf(v1.x); o1.y = f2bf(v1.y); o1.z = f2bf(v1.z); o1.w = f2bf(v1.w);
            uint4 o;
            o.x = (u32)o0.x | ((u32)o0.y << 16); o.y = (u32)o0.z | ((u32)o0.w << 16);
            o.z = (u32)o1.x | ((u32)o1.y << 16); o.w = (u32)o1.z | ((u32)o1.w << 16);
            *(uint4*)(xw + b64 * 64 + j * 8) = o;
        }
#pragma unroll
        for (int e = 0; e < NE; e++) {
#pragma unroll
            for (int o = 32; o >= 1; o >>= 1) acc[e] += __shfl_xor(acc[e], o, 64);
        }
        __syncthreads();
        if (lane == 0) {
            float mx = acc[0];
            for (int e = 1; e < NE; e++) mx = fmaxf(mx, acc[e]);
            float p[NE], sum = 0.f;
            for (int e = 0; e < NE; e++) { p[e] = expf(acc[e] - mx); sum += p[e]; }
            float inv = 1.f / sum;
            for (int e = 0; e < NE; e++) p[e] *= inv;
            int i1 = 0;
            for (int e = 1; e < NE; e++) if (p[e] > p[i1]) i1 = e;
            int i2 = (i1 == 0) ? 1 : 0;
            for (int e = 0; e < NE; e++) if (e != i1 && p[e] > p[i2]) i2 = e;
            tki[t * 2 + 0] = i1; tkv[t * 2 + 0] = p[i1];
            tki[t * 2 + 1] = i2; tkv[t * 2 + 1] = p[i2];
            for (int e = 0; e < NE; e++) atomicAdd(&s_imp[e], p[e]);
            atomicAdd(&s_cnt[i1], 1); atomicAdd(&s_cnt[i2], 1);
        }
        __syncthreads();
        if (tid < NE) {
            atomicAdd(&imp[tid], s_imp[tid]);
            atomicAdd(&counts[tid], s_cnt[tid]);
        }
    } else {
        // ---- transw(W1) part: [K=HD][N=ID] f32 -> [N][K'] bf16, perm'd k ----
        int tw = blockIdx.x - NT / 4;
        int e = tw / 704, rem = tw % 704;       // 704 = (ID/64=22) * (HD/64=32)
        int n0 = (rem % 22) * 64, k0 = (rem / 22) * 64;
        const float* src = (e < NE) ? (W1 + (size_t)e * HD * ID) : Ws1;
        u16* dst = wt1 + (size_t)e * ID * HD;
#pragma unroll
        for (int i = 0; i < 4; i++) {
            int idx = i * 256 + tid;
            int kl = idx >> 4, nq = (idx & 15) * 4;
            float4 v = *(const float4*)(src + (size_t)(k0 + kl) * ID + n0 + nq);
            Lt[nq + 0][kl] = f2bf(v.x); Lt[nq + 1][kl] = f2bf(v.y);
            Lt[nq + 2][kl] = f2bf(v.z); Lt[nq + 3][kl] = f2bf(v.w);
        }
        __syncthreads();
#pragma unroll
        for (int c2 = 0; c2 < 2; c2++) {
            int cid = tid * 2 + c2;
            int nr = cid >> 3, j = cid & 7;
            int h = j >> 2, q = j & 3;
            int kb = h * 32 + q * 4;
            uint2 lo = *(const uint2*)&Lt[nr][kb];
            uint2 hi = *(const uint2*)&Lt[nr][kb + 16];
            uint4 o; o.x = lo.x; o.y = lo.y; o.z = hi.x; o.w = hi.y;
            *(uint4*)(dst + (size_t)(n0 + nr) * HD + k0 + j * 8) = o;
        }
    }
}

// ---------------- prep + scatter fused (single block, LDS cursors) ----------
__global__ void prepscat_kernel(const int* __restrict__ counts, const float* __restrict__ imp,
                                int* __restrict__ off, int* __restrict__ tileoff,
                                float* __restrict__ out_aux,
                                int* __restrict__ tki, const float* __restrict__ tkv,
                                int* __restrict__ list, float* __restrict__ wgt) {
    __shared__ int s_off[NG];
    __shared__ int s_cur[NE];
    int tid = threadIdx.x;
    if (tid == 0) {
        int o = 0, to = 0;
        for (int g = 0; g < NG; g++) {
            int c = (g < NE) ? counts[g] : NT;
            off[g] = o; s_off[g] = o; tileoff[g] = to;
            o += c; to += (c + BM - 1) / BM;
        }
        off[NG] = o; tileoff[NG] = to;
        float aux = 0.f;
        for (int e = 0; e < NE; e++)
            aux += (imp[e] / (float)NT) * ((float)counts[e] / (float)(NT * TOPK));
        *out_aux = aux * (float)NE;
    }
    if (tid < NE) s_cur[tid] = 0;
    __syncthreads();
    for (int t = tid; t < NT; t += 256) {
#pragma unroll
        for (int k = 0; k < TOPK; k++) {
            int e = tki[t * 2 + k];
            int pos = atomicAdd(&s_cur[e], 1);
            int s = s_off[e] + pos;
            list[s] = t;
            wgt[s] = tkv[t * 2 + k];
            tki[t * 2 + k] = s;                 // slot map
        }
        list[s_off[NE] + t] = t;
        wgt[s_off[NE] + t] = 1.0f;
    }
}

// ---------------- transpose+convert weights (fallback W2 pass) --------------
__global__ void transw_kernel(const float* __restrict__ W, const float* __restrict__ Wsh,
                              u16* __restrict__ dst, int K, int N) {
    int e = blockIdx.z;
    const float* src = (e < NE) ? (W + (size_t)e * K * N) : Wsh;
    dst += (size_t)e * N * K;
    int k0 = blockIdx.y * 64, n0 = blockIdx.x * 64;
    __shared__ u16 Lt[64][68];
    int tid = threadIdx.x;
#pragma unroll
    for (int i = 0; i < 4; i++) {
        int idx = i * 256 + tid;
        int kl = idx >> 4, nq = (idx & 15) * 4;
        float4 v = *(const float4*)(src + (size_t)(k0 + kl) * N + n0 + nq);
        Lt[nq + 0][kl] = f2bf(v.x); Lt[nq + 1][kl] = f2bf(v.y);
        Lt[nq + 2][kl] = f2bf(v.z); Lt[nq + 3][kl] = f2bf(v.w);
    }
    __syncthreads();
#pragma unroll
    for (int c2 = 0; c2 < 2; c2++) {
        int cid = tid * 2 + c2;
        int nr = cid >> 3, j = cid & 7;
        int h = j >> 2, q = j & 3;
        int kb = h * 32 + q * 4;
        uint2 lo = *(const uint2*)&Lt[nr][kb];
        uint2 hi = *(const uint2*)&Lt[nr][kb + 16];
        uint4 o; o.x = lo.x; o.y = lo.y; o.z = hi.x; o.w = hi.y;
        *(uint4*)(dst + (size_t)(n0 + nr) * K + k0 + j * 8) = o;
    }
}

// ---------------- fc1: 192x128 tile, 768 thr (12 waves 3Mx4N), 80KB dbuf ----
// Per-wave 64x32 tile unchanged. 2 blocks/CU x 12 waves = 24 waves/CU.
// Waves 0-7 stage 2A+2B (vmcnt(4)); waves 8-11 stage 2A (vmcnt(2)).
// If FTW: blocks [NWG1, NWG1+NTW) transpose W2 -> wt2 (disjoint buffer).
template <bool FTW>
__global__ __launch_bounds__(768, 6) void fc1_kernel(
    const u16* __restrict__ xb, const u16* __restrict__ Wt1,
    const int* __restrict__ off, const int* __restrict__ tileoff,
    const int* __restrict__ list, u16* __restrict__ h1,
    const float* __restrict__ W2, const float* __restrict__ Ws2,
    u16* __restrict__ wt2) {
    __shared__ u16 S[2 * 20480];   // per buffer: A 192x64 (24KB) + B 128x64 (16KB)
    int wg0 = blockIdx.x;
    int tid = threadIdx.x;
    if (FTW && wg0 >= NWG1) {
        // ---- transw(W2): [K=ID][N=HD] f32 -> [N][K'] bf16, perm'd k --------
        u16 (*Lt)[68] = (u16(*)[68])S;
        int tw = wg0 - NWG1;
        int e = tw / 704, rem = tw % 704;       // 704 = (HD/64=32) * (ID/64=22)
        int n0 = (rem % 32) * 64, k0 = (rem / 32) * 64;
        const float* src = (e < NE) ? (W2 + (size_t)e * ID * HD) : Ws2;
        u16* dst = wt2 + (size_t)e * HD * ID;
#pragma unroll
        for (int i = 0; i < 2; i++) {
            int idx = i * 768 + tid;
            if (idx < 1024) {
                int kl = idx >> 4, nq = (idx & 15) * 4;
                float4 v = *(const float4*)(src + (size_t)(k0 + kl) * HD + n0 + nq);
                Lt[nq + 0][kl] = f2bf(v.x); Lt[nq + 1][kl] = f2bf(v.y);
                Lt[nq + 2][kl] = f2bf(v.z); Lt[nq + 3][kl] = f2bf(v.w);
            }
        }
        __syncthreads();
        if (tid < 512) {
            int nr = tid >> 3, j = tid & 7;
            int h = j >> 2, q = j & 3;
            int kb = h * 32 + q * 4;
            uint2 lo = *(const uint2*)&Lt[nr][kb];
            uint2 hi = *(const uint2*)&Lt[nr][kb + 16];
            uint4 o; o.x = lo.x; o.y = lo.y; o.z = hi.x; o.w = hi.y;
            *(uint4*)(dst + (size_t)(n0 + nr) * ID + kb * 2 - kb * 2 + k0 + j * 8) = o;
        }
        return;
    }
    // ---- GEMM part ----
    int wg = (wg0 & 7) * (NWG1 >> 3) + (wg0 >> 3);   // XCD swizzle, 792 %8==0
    int bx = wg % (ID / BN), mt = wg / (ID / BN);

    int g = -1, gto = 0;
#pragma unroll
    for (int gg = 0; gg < NG; gg++)
        if (mt >= tileoff[gg] && mt < tileoff[gg + 1]) { g = gg; gto = tileoff[gg]; }
    if (g < 0) return;
    int goff = off[g], cnt = off[g + 1] - goff;
    int row0 = (mt - gto) * BM;
    const u16* Wb = Wt1 + (size_t)g * (ID * HD);
    int n0 = bx * BN;
    int lane = tid & 63, w = tid >> 6;
    int r0 = tid >> 3;                           // 0..95
    int lc = (((tid & 7) ^ (r0 & 7)) << 3);      // swizzled source chunk
    int ra0 = row0 + r0;      ra0 = (ra0 < cnt) ? ra0 : (cnt - 1);
    int ra1 = row0 + 96 + r0; ra1 = (ra1 < cnt) ? ra1 : (cnt - 1);
    const u16* pa0 = xb + (size_t)list[goff + ra0] * HD + lc;
    const u16* pa1 = xb + (size_t)list[goff + ra1] * HD + lc;
    const u16* pb0 = nullptr; const u16* pb1 = nullptr;
    if (tid < 512) {
        pb0 = Wb + (size_t)(n0 + r0) * HD + lc;         // rows 0..63
        pb1 = Wb + (size_t)(n0 + 64 + r0) * HD + lc;    // rows 64..127
    }

    int wr = w >> 2, wc = w & 3;                 // 3M x 4N wave grid
    int lr = lane & 15, l7 = lane & 7, q2 = lane >> 4;
    f32x4 acc[4][2] = {};

    auto stage = [&](int b) {
        u16* A = S + b * 20480;
        u16* B = A + 12288;
        gl_lds16(pa0, A + tid * 8);        pa0 += BK;
        gl_lds16(pa1, A + 6144 + tid * 8); pa1 += BK;
        if (tid < 512) {
            gl_lds16(pb0, B + tid * 8);        pb0 += BK;
            gl_lds16(pb1, B + 4096 + tid * 8); pb1 += BK;
        }
    };
    auto compute = [&](int b) {
        const u16* A = S + b * 20480;
        const u16* B = A + 12288;
#pragma unroll
        for (int kc = 0; kc < 8; kc += 4) {
            int slot = ((kc + q2) ^ l7) << 3;
            bf16x8 a[4], bb[2];
#pragma unroll
            for (int f = 0; f < 4; f++)
                a[f] = __builtin_bit_cast(bf16x8, *(const uint4*)&A[(wr * 64 + f * 16 + lr) * BK + slot]);
#pragma unroll
            for (int f = 0; f < 2; f++)
                bb[f] = __builtin_bit_cast(bf16x8, *(const uint4*)&B[(wc * 32 + f * 16 + lr) * BK + slot]);
            __builtin_amdgcn_s_setprio(1);
#pragma unroll
            for (int mf = 0; mf < 4; mf++)
#pragma unroll
                for (int nf = 0; nf < 2; nf++)
                    acc[mf][nf] = __builtin_amdgcn_mfma_f32_16x16x32_bf16(a[mf], bb[nf], acc[mf][nf], 0, 0, 0);
            __builtin_amdgcn_s_setprio(0);
        }
    };

    bool heavy = (w < 8);
    stage(0);
    int cur = 0;
    for (int t = 1; t < HD / BK; ++t) {
        stage(cur ^ 1);
        if (heavy) asm volatile("s_waitcnt vmcnt(4)" ::: "memory");
        else       asm volatile("s_waitcnt vmcnt(2)" ::: "memory");
        __builtin_amdgcn_s_barrier();
        compute(cur);
        asm volatile("s_waitcnt lgkmcnt(0)" ::: "memory");
        __builtin_amdgcn_s_barrier();
        cur ^= 1;
    }
    asm volatile("s_waitcnt vmcnt(0)" ::: "memory");
    __builtin_amdgcn_s_barrier();
    compute(cur);

    int q4 = q2 * 4;
    int cl = ((lr >> 2) << 3) + (lr & 3);
#pragma unroll
    for (int mf = 0; mf < 4; mf++)
#pragma unroll
        for (int reg = 0; reg < 4; reg++) {
            int r = row0 + wr * 64 + mf * 16 + q4 + reg;
            if (r < cnt) {
                size_t rb = (size_t)(goff + r) * ID + n0;
#pragma unroll
                for (int nf = 0; nf < 2; nf++) {
                    float v = acc[mf][nf][reg];
                    h1[rb + wc * 32 + (nf << 2) + cl] = f2bf(v / (1.f + __expf(-v)));
                }
            }
        }
}

// ---------------- fc2: same geometry; EO -> eo stores, else atomic y --------
template <bool EO>
__global__ __launch_bounds__(768, 6) void fc2_kernel(
    const u16* __restrict__ h1, const u16* __restrict__ Wt2,
    const int* __restrict__ off, const int* __restrict__ tileoff,
    const int* __restrict__ list, const float* __restrict__ wgt,
    u16* __restrict__ eo, float* __restrict__ y) {
    __shared__ u16 S[2 * 20480];
    int wg0 = blockIdx.x;                        // NWG2 = 1152, %8==0
    int wg = (wg0 & 7) * (NWG2 >> 3) + (wg0 >> 3);
    int bx = wg % (HD / BN), mt = wg / (HD / BN);

    int g = -1, gto = 0;
#pragma unroll
    for (int gg = 0; gg < NG; gg++)
        if (mt >= tileoff[gg] && mt < tileoff[gg + 1]) { g = gg; gto = tileoff[gg]; }
    if (g < 0) return;
    int goff = off[g], cnt = off[g + 1] - goff;
    int row0 = (mt - gto) * BM;
    const u16* Wb = Wt2 + (size_t)g * (ID * HD);
    int n0 = bx * BN;
    int tid = threadIdx.x, lane = tid & 63, w = tid >> 6;
    int r0 = tid >> 3;
    int lc = (((tid & 7) ^ (r0 & 7)) << 3);
    int ra0 = row0 + r0;      ra0 = (ra0 < cnt) ? ra0 : (cnt - 1);
    int ra1 = row0 + 96 + r0; ra1 = (ra1 < cnt) ? ra1 : (cnt - 1);
    const u16* pa0 = h1 + (size_t)(goff + ra0) * ID + lc;    // slot-indexed, perm'd
    const u16* pa1 = h1 + (size_t)(goff + ra1) * ID + lc;
    const u16* pb0 = nullptr; const u16* pb1 = nullptr;
    if (tid < 512) {
        pb0 = Wb + (size_t)(n0 + r0) * ID + lc;
        pb1 = Wb + (size_t)(n0 + 64 + r0) * ID + lc;
    }

    int wr = w >> 2, wc = w & 3;
    int lr = lane & 15, l7 = lane & 7, q2 = lane >> 4;
    f32x4 acc[4][2] = {};

    auto stage = [&](int b) {
        u16* A = S + b * 20480;
        u16* B = A + 12288;
        gl_lds16(pa0, A + tid * 8);        pa0 += BK;
        gl_lds16(pa1, A + 6144 + tid * 8); pa1 += BK;
        if (tid < 512) {
            gl_lds16(pb0, B + tid * 8);        pb0 += BK;
            gl_lds16(pb1, B + 4096 + tid * 8); pb1 += BK;
        }
    };
    auto compute = [&](int b) {
        const u16* A = S + b * 20480;
        const u16* B = A + 12288;
#pragma unroll
        for (int kc = 0; kc < 8; kc += 4) {
            int slot = ((kc + q2) ^ l7) << 3;
            bf16x8 a[4], bb[2];
#pragma unroll
            for (int f = 0; f < 4; f++)
                a[f] = __builtin_bit_cast(bf16x8, *(const uint4*)&A[(wr * 64 + f * 16 + lr) * BK + slot]);
#pragma unroll
            for (int f = 0; f < 2; f++)
                bb[f] = __builtin_bit_cast(bf16x8, *(const uint4*)&B[(wc * 32 + f * 16 + lr) * BK + slot]);
            __builtin_amdgcn_s_setprio(1);
#pragma unroll
            for (int mf = 0; mf < 4; mf++)
#pragma unroll
                for (int nf = 0; nf < 2; nf++)
                    acc[mf][nf] = __builtin_amdgcn_mfma_f32_16x16x32_bf16(a[mf], bb[nf], acc[mf][nf], 0, 0, 0);
            __builtin_amdgcn_s_setprio(0);
        }
    };

    bool heavy = (w < 8);
    stage(0);
    int cur = 0;
    for (int t = 1; t < ID / BK; ++t) {
        stage(cur ^ 1);
        if (heavy) asm volatile("s_waitcnt vmcnt(4)" ::: "memory");
        else       asm volatile("s_waitcnt vmcnt(2)" ::: "memory");
        __builtin_amdgcn_s_barrier();
        compute(cur);
        asm volatile("s_waitcnt lgkmcnt(0)" ::: "memory");
        __builtin_amdgcn_s_barrier();
        cur ^= 1;
    }
    asm volatile("s_waitcnt vmcnt(0)" ::: "memory");
    __builtin_amdgcn_s_barrier();
    compute(cur);

    int q4 = q2 * 4;
#pragma unroll
    for (int mf = 0; mf < 4; mf++)
#pragma unroll
        for (int reg = 0; reg < 4; reg++) {
            int r = row0 + wr * 64 + mf * 16 + q4 + reg;
            if (r < cnt) {
                int slot = goff + r;
                if (EO) {
                    size_t rb = (size_t)slot * HD + n0 + wc * 32;
#pragma unroll
                    for (int nf = 0; nf < 2; nf++)
                        eo[rb + nf * 16 + lr] = f2bf(acc[mf][nf][reg]);
                } else {
                    int tok = list[slot];
                    float wv = wgt[slot];
                    float* yr = y + (size_t)tok * HD + n0 + wc * 32;
#pragma unroll
                    for (int nf = 0; nf < 2; nf++)
                        atomicAdd(yr + nf * 16 + lr, acc[mf][nf][reg] * wv);
                }
            }
        }
}

// ---------------- combine: y[t] = w0*eo[s0] + w1*eo[s1] + eo[shared] --------
__global__ __launch_bounds__(256) void combine_kernel(
    const u16* __restrict__ eo, const int* __restrict__ smap,
    const float* __restrict__ tkv, const int* __restrict__ off,
    float* __restrict__ y) {
    int idx = blockIdx.x * 256 + threadIdx.x;
    int t = idx >> 8;
    int cc = (idx & 255) << 3;
    int s0 = smap[t * 2 + 0], s1 = smap[t * 2 + 1];
    float w0 = tkv[t * 2 + 0], w1 = tkv[t * 2 + 1];
    int s2 = off[NE] + t;
    uint4 A = *(const uint4*)(eo + (size_t)s0 * HD + cc);
    uint4 B = *(const uint4*)(eo + (size_t)s1 * HD + cc);
    uint4 C = *(const uint4*)(eo + (size_t)s2 * HD + cc);
    float4 o0, o1;
    o0.x = w0 * bflo(A.x) + w1 * bflo(B.x) + bflo(C.x);
    o0.y = w0 * bfhi(A.x) + w1 * bfhi(B.x) + bfhi(C.x);
    o0.z = w0 * bflo(A.y) + w1 * bflo(B.y) + bflo(C.y);
    o0.w = w0 * bfhi(A.y) + w1 * bfhi(B.y) + bfhi(C.y);
    o1.x = w0 * bflo(A.z) + w1 * bflo(B.z) + bflo(C.z);
    o1.y = w0 * bfhi(A.z) + w1 * bfhi(B.z) + bfhi(C.z);
    o1.z = w0 * bflo(A.w) + w1 * bflo(B.w) + bflo(C.w);
    o1.w = w0 * bfhi(A.w) + w1 * bfhi(B.w) + bfhi(C.w);
    float* yr = y + (size_t)t * HD + cc;
    *(float4*)yr = o0;
    *(float4*)(yr + 4) = o1;
}

// ---------------- launch -----------------------------------------------------
extern "C" void kernel_launch(void* const* d_in, const int* in_sizes, int n_in,
                              void* d_out, int out_size, void* d_ws, size_t ws_size,
                              hipStream_t stream) {
    const float* x   = (const float*)d_in[0];
    const float* gw  = (const float*)d_in[1];
    const float* W1  = (const float*)d_in[2];
    const float* W2  = (const float*)d_in[3];
    const float* Ws1 = (const float*)d_in[4];
    const float* Ws2 = (const float*)d_in[5];
    float* out = (float*)d_out;

    char* ws = (char*)d_ws;
    int*   counts  = (int*)(ws + 0);
    int*   off     = (int*)(ws + 128);
    int*   tileoff = (int*)(ws + 192);
    float* imp     = (float*)(ws + 256);
    int*   tki     = (int*)(ws + 320);                    // becomes slot-map
    float* tkv     = (float*)(ws + 33088);
    int*   list    = (int*)(ws + 65856);
    float* wgt     = (float*)(ws + 115008);
    // big regions (bytes):
    //   xb  @ 164352        : 16,777,216
    //   Wt1 @ 16,941,568    : 51,904,512   (9 x 1408 x 2048 bf16)
    //   h1  @ 68,846,080    : 34,603,008   (12288 x 1408 bf16, perm'd cols)
    //   eo  @ 103,449,088   : 50,331,648   (12288 x 2048 bf16) -- if ws >= 153.8M
    //   Wt2: if ws >= 205,685,248 -> disjoint @153,780,736 (enables fc1-fusion)
    //        else aliases xb+Wt1 @164352 (serial transw2 after fc1)
    u16* xb  = (u16*)(ws + 164352);
    u16* wt1 = (u16*)(ws + 16941568ULL);
    u16* h1  = (u16*)(ws + 68846080ULL);
    u16* eo  = (u16*)(ws + 103449088ULL);
    const bool use_big = (ws_size >= 205685248ULL);
    const bool use_eo  = (ws_size >= 153780736ULL);
    u16* wt2 = use_big ? (u16*)(ws + 153780736ULL) : (u16*)(ws + 164352);

    if (!use_eo)
        hipMemsetAsync(d_out, 0, (size_t)out_size * sizeof(float), stream);
    hipMemsetAsync(d_ws, 0, 320, stream);

    // router (1024 blocks) || transw(W1) (6336 blocks) — independent work fused
    router_tw1_kernel<<<NT / 4 + NTW, 256, 0, stream>>>(
        x, gw, counts, imp, tki, tkv, xb, W1, Ws1, wt1);
    prepscat_kernel<<<1, 256, 0, stream>>>(
        counts, imp, off, tileoff, out + (size_t)NT * HD, tki, tkv, list, wgt);

    if (use_big) {
        // fc1 GEMM || transw(W2) fused — wt2 disjoint, rides fc1's spare BW
        fc1_kernel<true><<<NWG1 + NTW, 768, 0, stream>>>(
            xb, wt1, off, tileoff, list, h1, W2, Ws2, wt2);
    } else {
        fc1_kernel<false><<<NWG1, 768, 0, stream>>>(
            xb, wt1, off, tileoff, list, h1, W2, Ws2, wt2);
        // Wt2 overwrites xb/Wt1 (dead after fc1); stream order guarantees safety
        transw_kernel<<<dim3(HD / 64, ID / 64, NG), 256, 0, stream>>>(W2, Ws2, wt2, ID, HD);
    }

    if (use_eo) {
        fc2_kernel<true><<<NWG2, 768, 0, stream>>>(
            h1, wt2, off, tileoff, list, wgt, eo, out);
        combine_kernel<<<NT, 256, 0, stream>>>(eo, tki, tkv, off, out);
    } else {
        fc2_kernel<false><<<NWG2, 768, 0, stream>>>(
            h1, wt2, off, tileoff, list, wgt, eo, out);
    }
}